// Round 5
// baseline (282.897 us; speedup 1.0000x reference)
//
#include <hip/hip_runtime.h>
#include <math.h>

// Problem constants
#define B2     2
#define CIN    31
#define CC     64      // conv out channels / GAT dim
#define NN     4096    // 64*64 nodes
#define NCH    8       // kNN j-splits (512 j each)

typedef short bf16x8 __attribute__((ext_vector_type(8)));
typedef float f32x4  __attribute__((ext_vector_type(4)));

__device__ inline unsigned short f2bf(float f) {
  union { float f; unsigned u; } v; v.f = f;
  unsigned r = (v.u + 0x7fffu + ((v.u >> 16) & 1u)) >> 16;
  return (unsigned short)r;
}
__device__ inline float bf2f(unsigned short h) {
  union { float f; unsigned u; } v; v.u = ((unsigned)h) << 16;
  return v.f;
}

// ---------------- workspace layout (in 4-byte elements) ----------------
constexpr int OF_YN   = 0;                         // [B,N,64] fp32
constexpr int OF_SQ   = OF_YN   + B2*NN*CC;        // [B,N]
constexpr int OF_HCAT = OF_SQ   + B2*NN;           // [B,N,128]
constexpr int OF_FV   = OF_HCAT + B2*NN*128;       // 4 x [B*N]
constexpr int OF_HAGG = OF_FV   + 4*B2*NN;         // [B,N,128]
constexpr int OF_HO   = OF_HAGG + B2*NN*128;       // [B,N,64]
constexpr int OF_FO   = OF_HO   + B2*NN*CC;        // 2 x [B*N]
constexpr int OF_Z    = OF_FO   + 2*B2*NN;         // [B,N,64]
constexpr int OF_PD   = OF_Z    + B2*NN*CC;        // partial top7 dists [B*N][NCH][7]
constexpr int OF_PI   = OF_PD   + B2*NN*NCH*7;     // partial top7 idx (int)
constexpr int OF_NBR  = OF_PI   + B2*NN*NCH*7;     // [B*N][7] neighbor idx (int)
constexpr int OF_WT   = OF_NBR  + B2*NN*7;         // convT weights [9][64][64]
constexpr int OF_WHT  = OF_WT   + 9*64*64;         // head conv weights [279][64]
constexpr int OF_YNH  = OF_WHT  + 279*64;          // bf16 hi [B,N,64] (ushort)
constexpr int OF_YNL  = OF_YNH  + B2*NN*CC/2;      // bf16 lo [B,N,64] (ushort)

// ---------------- K0: weight transposes ----------------
__global__ __launch_bounds__(256) void k_prep(const float* __restrict__ wlast,
                                              const float* __restrict__ whead,
                                              float* __restrict__ wT,
                                              float* __restrict__ whT) {
  int idx = blockIdx.x*256 + threadIdx.x;
  if (idx < 36864) {
    int co = idx & 63, ci = (idx >> 6) & 63, kk = idx >> 12;
    wT[idx] = wlast[(ci*64 + co)*9 + kk];
  } else if (idx < 36864 + 279*64) {
    int j = idx - 36864;
    int c = j & 63, q = j >> 6;
    whT[j] = whead[c*279 + q];
  }
}

// ---------------- K1: head conv (31->64, k3 s2 p1) + sq + bf16 split --------
__global__ __launch_bounds__(256) void k_head(const float* __restrict__ x,
                                              const float* __restrict__ whT,
                                              const float* __restrict__ bias,
                                              float* __restrict__ yn,
                                              float* __restrict__ sq,
                                              unsigned short* __restrict__ ynh,
                                              unsigned short* __restrict__ ynl) {
  int lane = threadIdx.x & 63, wv = threadIdx.x >> 6;
  int gbase = blockIdx.x*32 + wv*8;
  __shared__ float patch[4][8][280];
  for (int nn = 0; nn < 8; ++nn) {
    int g = gbase + nn;
    int b = g >> 12, n = g & 4095;
    int oh = n >> 6, ow = n & 63;
    for (int q = lane; q < 279; q += 64) {
      int ci = q / 9, r = q - ci*9;
      int ky = r / 3, kx = r - ky*3;
      int ih = 2*oh - 1 + ky, iw = 2*ow - 1 + kx;
      float v = 0.f;
      if (ih >= 0 && ih < 128 && iw >= 0 && iw < 128)
        v = x[((b*CIN + ci)*128 + ih)*128 + iw];
      patch[wv][nn][q] = v;
    }
  }
  __syncthreads();
  int c = lane;
  float acc[8];
  float bv = bias[c];
  #pragma unroll
  for (int nn = 0; nn < 8; ++nn) acc[nn] = bv;
  for (int q = 0; q < 279; ++q) {
    float wgt = whT[q*64 + c];
    #pragma unroll
    for (int nn = 0; nn < 8; ++nn) acc[nn] += patch[wv][nn][q] * wgt;
  }
  for (int nn = 0; nn < 8; ++nn) {
    int g = gbase + nn;
    float y = acc[nn];
    yn[g*64 + c] = y;
    unsigned short hb = f2bf(y);
    ynh[g*64 + c] = hb;
    ynl[g*64 + c] = f2bf(y - bf2f(hb));
    float s = y*y;
    #pragma unroll
    for (int off = 32; off > 0; off >>= 1) s += __shfl_xor(s, off);
    if (lane == 0) sq[g] = s;
  }
}

// ---------------- K2: register-resident MFMA Gram + in-register top-7 -------
// grid (64 i-blocks of 64 rows, NCH j-splits of 512, 2 batches), 256 threads.
// No LDS staging, no barriers in the main loop: j-side fragments stream from
// global (L2-resident, coalesced 16B/lane); each lane's acc holds 16 j-dists
// for ONE i-row (C col=lane&15 -> i, row=quad*4+r -> j); top-7 kept in regs.
__global__ __launch_bounds__(256, 4) void k_knn4(const unsigned short* __restrict__ ynh,
                                                 const unsigned short* __restrict__ ynl,
                                                 const float* __restrict__ sq,
                                                 float* __restrict__ pd,
                                                 int* __restrict__ pidx) {
  __shared__ float cd[64*28];
  __shared__ int   ci[64*28];

  int b = blockIdx.z, ib = blockIdx.x, jsp = blockIdx.y;
  int i0 = ib*64, jbase = jsp*512;
  int tid = threadIdx.x;
  int lane = tid & 63, w = tid >> 6;
  int quad = lane >> 4, m = lane & 15;

  const unsigned short* ynh_b = ynh + (size_t)b*NN*64;
  const unsigned short* ynl_b = ynl + (size_t)b*NN*64;
  const float* sq_b = sq + b*NN;

  // i-side fragments (MFMA B-operand), held in registers for the whole kernel
  int irow = i0 + w*16 + m;
  bf16x8 bhf0 = *(const bf16x8*)(ynh_b + irow*64 + quad*8);
  bf16x8 bhf1 = *(const bf16x8*)(ynh_b + irow*64 + 32 + quad*8);
  bf16x8 blf0 = *(const bf16x8*)(ynl_b + irow*64 + quad*8);
  bf16x8 blf1 = *(const bf16x8*)(ynl_b + irow*64 + 32 + quad*8);
  float sqi = sq_b[irow];

  float d7[7]; int x7[7];
  #pragma unroll
  for (int k = 0; k < 7; ++k) { d7[k] = 3.0e38f; x7[k] = 0x7fffffff; }

  #pragma unroll 1
  for (int c = 0; c < 8; ++c) {
    int jt = jbase + c*64;
    #pragma unroll
    for (int jn = 0; jn < 4; ++jn) {
      int jr = jt + jn*16;
      const unsigned short* ahp = ynh_b + (jr + m)*64 + quad*8;
      const unsigned short* alp = ynl_b + (jr + m)*64 + quad*8;
      bf16x8 ajh0 = *(const bf16x8*)ahp;
      bf16x8 ajh1 = *(const bf16x8*)(ahp + 32);
      bf16x8 ajl0 = *(const bf16x8*)alp;
      bf16x8 ajl1 = *(const bf16x8*)(alp + 32);
      f32x4 sq4 = *(const f32x4*)(sq_b + jr + quad*4);

      f32x4 a = (f32x4){0.f, 0.f, 0.f, 0.f};
      a = __builtin_amdgcn_mfma_f32_16x16x32_bf16(ajh0, bhf0, a, 0, 0, 0);
      a = __builtin_amdgcn_mfma_f32_16x16x32_bf16(ajl0, bhf0, a, 0, 0, 0);
      a = __builtin_amdgcn_mfma_f32_16x16x32_bf16(ajh0, blf0, a, 0, 0, 0);
      a = __builtin_amdgcn_mfma_f32_16x16x32_bf16(ajh1, bhf1, a, 0, 0, 0);
      a = __builtin_amdgcn_mfma_f32_16x16x32_bf16(ajl1, bhf1, a, 0, 0, 0);
      a = __builtin_amdgcn_mfma_f32_16x16x32_bf16(ajh1, blf1, a, 0, 0, 0);

      float d2[4];
      #pragma unroll
      for (int r = 0; r < 4; ++r) d2[r] = fmaf(-2.f, a[r], sqi + sq4[r]);
      float mn = fminf(fminf(d2[0], d2[1]), fminf(d2[2], d2[3]));
      if (mn < d7[6]) {
        #pragma unroll
        for (int r = 0; r < 4; ++r) {
          float d = d2[r];
          if (d < d7[6]) {                 // strict < : ascending j stable
            int jj = jr + quad*4 + r;
            int k = 6;
            #pragma unroll
            for (int t = 5; t >= 0; --t)
              if (d < d7[t]) { d7[t+1] = d7[t]; x7[t+1] = x7[t]; k = t; }
            d7[k] = d; x7[k] = jj;
          }
        }
      }
    }
  }

  // merge across the 4 quads of each i-row (tie-break by index)
  int row = w*16 + m;
  #pragma unroll
  for (int k = 0; k < 7; ++k) {
    cd[row*28 + quad*7 + k] = d7[k];
    ci[row*28 + quad*7 + k] = x7[k];
  }
  __syncthreads();
  if (tid < 64) {
    float md[7]; int mi[7];
    #pragma unroll
    for (int k = 0; k < 7; ++k) { md[k] = 3.0e38f; mi[k] = 0x7fffffff; }
    for (int e = 0; e < 28; ++e) {
      float d = cd[tid*28 + e]; int jj = ci[tid*28 + e];
      if (d < md[6] || (d == md[6] && jj < mi[6])) {
        int k = 6;
        #pragma unroll
        for (int t = 5; t >= 0; --t)
          if (d < md[t] || (d == md[t] && jj < mi[t])) { md[t+1] = md[t]; mi[t+1] = mi[t]; k = t; }
        md[k] = d; mi[k] = jj;
      }
    }
    int g = b*NN + i0 + tid;
    int base = (g*NCH + jsp)*7;
    #pragma unroll
    for (int k = 0; k < 7; ++k) { pd[base+k] = md[k]; pidx[base+k] = mi[k]; }
  }
}

// ---------------- K3: merge per-split top7 -> final 7 neighbors --------------
__global__ __launch_bounds__(256) void k_merge(const float* __restrict__ pd,
                                               const int* __restrict__ pidx,
                                               int* __restrict__ nbr) {
  int g = blockIdx.x*256 + threadIdx.x;
  float d7[7]; int x7[7];
  #pragma unroll
  for (int k = 0; k < 7; ++k) { d7[k] = 3.0e38f; x7[k] = 0x7fffffff; }
  int base = g*NCH*7;
  for (int e = 0; e < NCH*7; ++e) {
    float d = pd[base+e]; int jj = pidx[base+e];
    if (d < d7[6]) {
      int k = 6;
      #pragma unroll
      for (int t = 5; t >= 0; --t) {
        if (d < d7[t]) { d7[t+1] = d7[t]; x7[t+1] = x7[t]; k = t; }
      }
      d7[k] = d; x7[k] = jj;
    }
  }
  #pragma unroll
  for (int k = 0; k < 7; ++k) nbr[g*7 + k] = x7[k];
}

// ---------------- K4: hcat = yn @ [W0|W1] + fused f-vectors -----------------
__global__ __launch_bounds__(256) void k_hcat(const float* __restrict__ yn,
                                              const float* __restrict__ W0,
                                              const float* __restrict__ W1,
                                              const float* __restrict__ a0,
                                              const float* __restrict__ a1,
                                              float* __restrict__ hcat,
                                              float* __restrict__ fv) {
  __shared__ float Ws[64*128];
  __shared__ float yt[16*64];
  int b = blockIdx.x >> 8, n0 = (blockIdx.x & 255)*16;
  int tid = threadIdx.x;
  for (int idx = tid; idx < 8192; idx += 256) {
    int k = idx >> 7, c = idx & 127;
    Ws[idx] = (c < 64) ? W0[k*64 + c] : W1[k*64 + (c - 64)];
  }
  {
    const float4* src = (const float4*)(yn + (b*NN + n0)*64);
    for (int idx = tid; idx < 256; idx += 256) ((float4*)yt)[idx] = src[idx];
  }
  __syncthreads();
  int c = tid & 127, nh = tid >> 7;
  int lane = tid & 63;
  int head = (c >= 64);
  float av1 = head ? a1[lane] : a0[lane];
  float av2 = head ? a1[64 + lane] : a0[64 + lane];
  for (int nn = 0; nn < 8; ++nn) {
    int node = nh*8 + nn;
    const float* yr = yt + node*64;
    float acc = 0.f;
    #pragma unroll
    for (int k = 0; k < 64; ++k) acc += yr[k] * Ws[k*128 + c];
    hcat[(b*NN + n0 + node)*128 + c] = acc;
    float s1 = acc*av1, s2 = acc*av2;
    #pragma unroll
    for (int off = 32; off > 0; off >>= 1) {
      s1 += __shfl_xor(s1, off); s2 += __shfl_xor(s2, off);
    }
    if (lane == 0) {
      int gg = (b << 12) + n0 + node;
      fv[head*16384 + gg] = s1;
      fv[head*16384 + 8192 + gg] = s2;
    }
  }
}

// ---------------- K6: GAT layer1 aggregation (2 heads) + relu ---------------
__global__ __launch_bounds__(256) void k_agg1(const float* __restrict__ hcat,
                                              const float* __restrict__ fv,
                                              const int* __restrict__ nbr,
                                              float* __restrict__ hagg) {
  int g = blockIdx.x*2 + (threadIdx.x >> 7);
  int c = threadIdx.x & 127;
  int b = g >> 12;
  int head = c >> 6;
  int jj[7];
  #pragma unroll
  for (int t = 0; t < 7; ++t) jj[t] = nbr[g*7 + t];
  float f1 = fv[head*16384 + g];
  const float* f2p = fv + head*16384 + 8192 + (b << 12);
  float e[7], mx = -3.0e38f;
  #pragma unroll
  for (int t = 0; t < 7; ++t) {
    float v = f1 + f2p[jj[t]];
    v = (v >= 0.f) ? v : 0.2f*v;
    e[t] = v; mx = fmaxf(mx, v);
  }
  float wgt[7], s = 0.f;
  #pragma unroll
  for (int t = 0; t < 7; ++t) { wgt[t] = expf(e[t] - mx); s += wgt[t]; }
  float acc = 0.f;
  #pragma unroll
  for (int t = 0; t < 7; ++t)
    acc += (wgt[t]/s) * hcat[((b << 12) + jj[t])*128 + c];
  hagg[g*128 + c] = fmaxf(acc, 0.f);
}

// ---------------- K7: ho = hagg @ W_out + fused f-vectors -------------------
__global__ __launch_bounds__(256) void k_ho(const float* __restrict__ hagg,
                                            const float* __restrict__ Wout,
                                            const float* __restrict__ aout,
                                            float* __restrict__ ho,
                                            float* __restrict__ fo) {
  __shared__ float Ws[128*64];
  __shared__ float ht[16*128];
  int b = blockIdx.x >> 8, n0 = (blockIdx.x & 255)*16;
  int tid = threadIdx.x;
  for (int idx = tid; idx < 8192; idx += 256) Ws[idx] = Wout[idx];
  {
    const float4* src = (const float4*)(hagg + (b*NN + n0)*128);
    for (int idx = tid; idx < 512; idx += 256) ((float4*)ht)[idx] = src[idx];
  }
  __syncthreads();
  int c = tid & 63, ngrp = tid >> 6;
  float av1 = aout[c], av2 = aout[64 + c];
  for (int nn = 0; nn < 4; ++nn) {
    int node = ngrp*4 + nn;
    const float* hr = ht + node*128;
    float acc = 0.f;
    #pragma unroll
    for (int k = 0; k < 128; ++k) acc += hr[k] * Ws[k*64 + c];
    ho[(b*NN + n0 + node)*64 + c] = acc;
    float s1 = acc*av1, s2 = acc*av2;
    #pragma unroll
    for (int off = 32; off > 0; off >>= 1) {
      s1 += __shfl_xor(s1, off); s2 += __shfl_xor(s2, off);
    }
    if (c == 0) {
      int gg = (b << 12) + n0 + node;
      fo[gg] = s1;
      fo[8192 + gg] = s2;
    }
  }
}

// ---------------- K9: layer2 agg + elu + log_softmax ------------------------
__global__ __launch_bounds__(256) void k_agg2(const float* __restrict__ ho,
                                              const float* __restrict__ fo,
                                              const int* __restrict__ nbr,
                                              float* __restrict__ zbuf) {
  int g = blockIdx.x*4 + (threadIdx.x >> 6);
  int c = threadIdx.x & 63;
  int b = g >> 12;
  int jj[7];
  #pragma unroll
  for (int t = 0; t < 7; ++t) jj[t] = nbr[g*7 + t];
  float f1 = fo[g];
  const float* f2p = fo + 8192 + (b << 12);
  float e[7], mx = -3.0e38f;
  #pragma unroll
  for (int t = 0; t < 7; ++t) {
    float v = f1 + f2p[jj[t]];
    v = (v >= 0.f) ? v : 0.2f*v;
    e[t] = v; mx = fmaxf(mx, v);
  }
  float wgt[7], s = 0.f;
  #pragma unroll
  for (int t = 0; t < 7; ++t) { wgt[t] = expf(e[t] - mx); s += wgt[t]; }
  float acc = 0.f;
  #pragma unroll
  for (int t = 0; t < 7; ++t)
    acc += (wgt[t]/s) * ho[((b << 12) + jj[t])*64 + c];
  float v = (acc > 0.f) ? acc : expm1f(acc);
  float mm = v;
  #pragma unroll
  for (int off = 32; off > 0; off >>= 1) mm = fmaxf(mm, __shfl_xor(mm, off));
  float ex = expf(v - mm), ss = ex;
  #pragma unroll
  for (int off = 32; off > 0; off >>= 1) ss += __shfl_xor(ss, off);
  zbuf[g*64 + c] = v - mm - logf(ss);
}

// ---------------- K10: ConvTranspose2d v2 — per-row tap-looped LDS matmul ---
__global__ __launch_bounds__(256) void k_convt2(const float* __restrict__ z,
                                                const float* __restrict__ wT,
                                                const float* __restrict__ bias,
                                                float* __restrict__ out) {
  __shared__ __align__(16) float lds[12800];   // 51200 B
  float* zt = lds;              // [2 rows][64 ci][68]
  float* ws = lds + 8704;       // [64 ci][64 co]
  float* so = lds;              // [64 co][129] epilogue alias

  int oy = blockIdx.x, b = blockIdx.y;
  int r = oy >> 1, pi = oy & 1;
  int tid = threadIdx.x;
  int colo = tid & 15, pgrp = tid >> 4;
  int co4 = colo*4, m0 = pgrp*4;

  int nrows = pi ? 2 : 1;
  for (int row = 0; row < nrows; ++row) {
    int iy = r + row;
    const float* zsrc = z + (((b << 12) + iy*64) << 6);
    for (int idx = tid; idx < 4352; idx += 256) {
      int ix = idx >> 6, ci = idx & 63;
      float v = 0.f;
      if (ix < 64 && iy < 64) v = zsrc[ix*64 + ci];
      zt[row*4352 + ci*68 + ix] = v;
    }
  }

  float acc[2][4][4];
  {
    float4 bv = *(const float4*)&bias[co4];
    #pragma unroll
    for (int chi = 0; chi < 2; ++chi)
      #pragma unroll
      for (int k = 0; k < 4; ++k) {
        acc[chi][k][0] = bv.x; acc[chi][k][1] = bv.y;
        acc[chi][k][2] = bv.z; acc[chi][k][3] = bv.w;
      }
  }

  int kys[2], rows[2], nky;
  if (pi == 0) { kys[0] = 1; rows[0] = 0; nky = 1; }
  else         { kys[0] = 2; rows[0] = 0; kys[1] = 0; rows[1] = 1; nky = 2; }

  for (int t = 0; t < nky; ++t) {
    const float* zrow = zt + rows[t]*4352;
    for (int kx = 0; kx < 3; ++kx) {
      const float* wsrc = wT + (kys[t]*3 + kx)*4096;
      __syncthreads();
      for (int idx = tid; idx < 4096; idx += 256) ws[idx] = wsrc[idx];
      __syncthreads();
      int chi = (kx == 1) ? 0 : 1;
      int xoff = (kx == 0) ? 1 : 0;
      float* ap = &acc[chi][0][0];
      for (int ci = 0; ci < 64; ++ci) {
        float4 wv = *(const float4*)&ws[ci*64 + co4];
        const float* zp = zrow + ci*68 + m0;
        float4 zv;
        if (xoff == 0) {
          zv = *(const float4*)zp;
        } else {
          float4 a0 = *(const float4*)zp;
          float4 a1 = *(const float4*)(zp + 4);
          zv.x = a0.y; zv.y = a0.z; zv.z = a0.w; zv.w = a1.x;
        }
        #pragma unroll
        for (int k = 0; k < 4; ++k) {
          float zk = (&zv.x)[k];
          ap[k*4+0] += zk * wv.x;
          ap[k*4+1] += zk * wv.y;
          ap[k*4+2] += zk * wv.z;
          ap[k*4+3] += zk * wv.w;
        }
      }
    }
  }

  __syncthreads();
  #pragma unroll
  for (int chi = 0; chi < 2; ++chi)
    #pragma unroll
    for (int k = 0; k < 4; ++k)
      #pragma unroll
      for (int cc = 0; cc < 4; ++cc)
        so[(co4 + cc)*129 + 2*(m0 + k) + chi] = acc[chi][k][cc];
  __syncthreads();
  for (int idx = tid; idx < 8192; idx += 256) {
    int co = idx >> 7, ox = idx & 127;
    out[(((b << 6) + co)*128 + oy)*128 + ox] = so[co*129 + ox];
  }
}

// ---------------- launch ----------------------------------------------------
extern "C" void kernel_launch(void* const* d_in, const int* in_sizes, int n_in,
                              void* d_out, int out_size, void* d_ws, size_t ws_size,
                              hipStream_t stream) {
  const float* x      = (const float*)d_in[0];
  const float* w_head = (const float*)d_in[1];
  const float* b_head = (const float*)d_in[2];
  const float* W0     = (const float*)d_in[3];
  const float* a0     = (const float*)d_in[4];
  const float* W1     = (const float*)d_in[5];
  const float* a1     = (const float*)d_in[6];
  const float* W_out  = (const float*)d_in[7];
  const float* a_out  = (const float*)d_in[8];
  const float* w_last = (const float*)d_in[9];
  const float* b_last = (const float*)d_in[10];
  float* out = (float*)d_out;

  float* wsf = (float*)d_ws;
  int*   wsi = (int*)d_ws;
  float* yn   = wsf + OF_YN;
  float* sq   = wsf + OF_SQ;
  float* hcat = wsf + OF_HCAT;
  float* fv   = wsf + OF_FV;
  float* hagg = wsf + OF_HAGG;
  float* ho   = wsf + OF_HO;
  float* fo   = wsf + OF_FO;
  float* zbuf = wsf + OF_Z;
  float* pd   = wsf + OF_PD;
  int*   pidx = wsi + OF_PI;
  int*   nbr  = wsi + OF_NBR;
  float* wT   = wsf + OF_WT;
  float* whT  = wsf + OF_WHT;
  unsigned short* ynh = (unsigned short*)(wsf + OF_YNH);
  unsigned short* ynl = (unsigned short*)(wsf + OF_YNL);

  hipLaunchKernelGGL(k_prep,  dim3(214), dim3(256), 0, stream, w_last, w_head, wT, whT);
  hipLaunchKernelGGL(k_head,  dim3(256), dim3(256), 0, stream, x, whT, b_head, yn, sq, ynh, ynl);
  hipLaunchKernelGGL(k_knn4,  dim3(64, NCH, 2), dim3(256), 0, stream, ynh, ynl, sq, pd, pidx);
  hipLaunchKernelGGL(k_merge, dim3(32), dim3(256), 0, stream, pd, pidx, nbr);
  hipLaunchKernelGGL(k_hcat,  dim3(512), dim3(256), 0, stream, yn, W0, W1, a0, a1, hcat, fv);
  hipLaunchKernelGGL(k_agg1,  dim3(4096), dim3(256), 0, stream, hcat, fv, nbr, hagg);
  hipLaunchKernelGGL(k_ho,    dim3(512), dim3(256), 0, stream, hagg, W_out, a_out, ho, fo);
  hipLaunchKernelGGL(k_agg2,  dim3(2048), dim3(256), 0, stream, ho, fo, nbr, zbuf);
  hipLaunchKernelGGL(k_convt2, dim3(128, 2), dim3(256), 0, stream, zbuf, wT, b_last, out);
}

// Round 6
// 270.541 us; speedup vs baseline: 1.0457x; 1.0457x over previous
//
#include <hip/hip_runtime.h>
#include <math.h>

// Problem constants
#define B2     2
#define CIN    31
#define CC     64      // conv out channels / GAT dim
#define NN     4096    // 64*64 nodes
#define NCH    8       // kNN j-splits (512 j each)

typedef short bf16x8 __attribute__((ext_vector_type(8)));
typedef float f32x4  __attribute__((ext_vector_type(4)));

__device__ inline unsigned short f2bf(float f) {
  union { float f; unsigned u; } v; v.f = f;
  unsigned r = (v.u + 0x7fffu + ((v.u >> 16) & 1u)) >> 16;
  return (unsigned short)r;
}
__device__ inline float bf2f(unsigned short h) {
  union { float f; unsigned u; } v; v.u = ((unsigned)h) << 16;
  return v.f;
}

// ---------------- workspace layout (in 4-byte elements) ----------------
constexpr int OF_YN   = 0;                         // [B,N,64] fp32
constexpr int OF_SQ   = OF_YN   + B2*NN*CC;        // [B,N]
constexpr int OF_HCAT = OF_SQ   + B2*NN;           // [B,N,128]
constexpr int OF_FV   = OF_HCAT + B2*NN*128;       // 4 x [B*N]
constexpr int OF_HAGG = OF_FV   + 4*B2*NN;         // [B,N,128]
constexpr int OF_HO   = OF_HAGG + B2*NN*128;       // [B,N,64]
constexpr int OF_FO   = OF_HO   + B2*NN*CC;        // 2 x [B*N]
constexpr int OF_Z    = OF_FO   + 2*B2*NN;         // [B,N,64]
constexpr int OF_PD   = OF_Z    + B2*NN*CC;        // partial top7 dists [B*N][NCH][7]
constexpr int OF_PI   = OF_PD   + B2*NN*NCH*7;     // partial top7 idx (int)
constexpr int OF_NBR  = OF_PI   + B2*NN*NCH*7;     // [B*N][7] neighbor idx (int)
constexpr int OF_WT   = OF_NBR  + B2*NN*7;         // convT weights [9][64][64]
constexpr int OF_WHT  = OF_WT   + 9*64*64;         // head conv weights [279][64]
constexpr int OF_YNH  = OF_WHT  + 279*64;          // bf16 hi [B,N,64] (ushort)
constexpr int OF_YNL  = OF_YNH  + B2*NN*CC/2;      // bf16 lo [B,N,64] (ushort)

// ---------------- K0: weight transposes ----------------
__global__ __launch_bounds__(256) void k_prep(const float* __restrict__ wlast,
                                              const float* __restrict__ whead,
                                              float* __restrict__ wT,
                                              float* __restrict__ whT) {
  int idx = blockIdx.x*256 + threadIdx.x;
  if (idx < 36864) {
    int co = idx & 63, ci = (idx >> 6) & 63, kk = idx >> 12;
    wT[idx] = wlast[(ci*64 + co)*9 + kk];
  } else if (idx < 36864 + 279*64) {
    int j = idx - 36864;
    int c = j & 63, q = j >> 6;
    whT[j] = whead[c*279 + q];
  }
}

// ---------------- K1: head conv + sq + bf16 split (float4 LDS reads) --------
__global__ __launch_bounds__(256) void k_head(const float* __restrict__ x,
                                              const float* __restrict__ whT,
                                              const float* __restrict__ bias,
                                              float* __restrict__ yn,
                                              float* __restrict__ sq,
                                              unsigned short* __restrict__ ynh,
                                              unsigned short* __restrict__ ynl) {
  int lane = threadIdx.x & 63, wv = threadIdx.x >> 6;
  int gbase = blockIdx.x*32 + wv*8;
  __shared__ __align__(16) float patch[4][8][280];
  for (int nn = 0; nn < 8; ++nn) {
    int g = gbase + nn;
    int b = g >> 12, n = g & 4095;
    int oh = n >> 6, ow = n & 63;
    for (int q = lane; q < 279; q += 64) {
      int ci = q / 9, r = q - ci*9;
      int ky = r / 3, kx = r - ky*3;
      int ih = 2*oh - 1 + ky, iw = 2*ow - 1 + kx;
      float v = 0.f;
      if (ih >= 0 && ih < 128 && iw >= 0 && iw < 128)
        v = x[((b*CIN + ci)*128 + ih)*128 + iw];
      patch[wv][nn][q] = v;
    }
  }
  __syncthreads();
  int c = lane;
  float acc[8];
  float bv = bias[c];
  #pragma unroll
  for (int nn = 0; nn < 8; ++nn) acc[nn] = bv;
  for (int q = 0; q < 276; q += 4) {
    float w0 = whT[q*64 + c];
    float w1 = whT[(q+1)*64 + c];
    float w2 = whT[(q+2)*64 + c];
    float w3 = whT[(q+3)*64 + c];
    #pragma unroll
    for (int nn = 0; nn < 8; ++nn) {
      float4 pv = *(const float4*)&patch[wv][nn][q];
      acc[nn] = fmaf(pv.x, w0, acc[nn]);
      acc[nn] = fmaf(pv.y, w1, acc[nn]);
      acc[nn] = fmaf(pv.z, w2, acc[nn]);
      acc[nn] = fmaf(pv.w, w3, acc[nn]);
    }
  }
  for (int q = 276; q < 279; ++q) {
    float wq = whT[q*64 + c];
    #pragma unroll
    for (int nn = 0; nn < 8; ++nn) acc[nn] = fmaf(patch[wv][nn][q], wq, acc[nn]);
  }
  for (int nn = 0; nn < 8; ++nn) {
    int g = gbase + nn;
    float y = acc[nn];
    yn[g*64 + c] = y;
    unsigned short hb = f2bf(y);
    ynh[g*64 + c] = hb;
    ynl[g*64 + c] = f2bf(y - bf2f(hb));
    float s = y*y;
    #pragma unroll
    for (int off = 32; off > 0; off >>= 1) s += __shfl_xor(s, off);
    if (lane == 0) sq[g] = s;
  }
}

// ---------------- K2: LDS-staged (dbuf) MFMA Gram + in-register top-7 -------
// grid (64 i-blocks of 64 rows, NCH j-splits of 512, 2 batches), 256 threads.
// j-tiles staged once per block into double-buffered LDS (1 barrier/chunk);
// each lane's acc holds 16 j-dists for ONE i-row; top-7 kept in registers.
__global__ __launch_bounds__(256, 4) void k_knn5(const unsigned short* __restrict__ ynh,
                                                 const unsigned short* __restrict__ ynl,
                                                 const float* __restrict__ sq,
                                                 float* __restrict__ pd,
                                                 int* __restrict__ pidx) {
  __shared__ __align__(16) unsigned short Bh[2][64*72];   // 18432 B
  __shared__ __align__(16) unsigned short Bl[2][64*72];   // 18432 B
  __shared__ __align__(16) float sqjs[2][64];             // 512 B

  int b = blockIdx.z, ib = blockIdx.x, jsp = blockIdx.y;
  int i0 = ib*64, jbase = jsp*512;
  int tid = threadIdx.x;
  int lane = tid & 63, w = tid >> 6;
  int quad = lane >> 4, m = lane & 15;

  const unsigned short* ynh_b = ynh + (size_t)b*NN*64;
  const unsigned short* ynl_b = ynl + (size_t)b*NN*64;
  const float* sq_b = sq + b*NN;

  // i-side fragments (MFMA B-operand), registers for the whole kernel
  int irow = i0 + w*16 + m;
  bf16x8 bhf0 = *(const bf16x8*)(ynh_b + irow*64 + quad*8);
  bf16x8 bhf1 = *(const bf16x8*)(ynh_b + irow*64 + 32 + quad*8);
  bf16x8 blf0 = *(const bf16x8*)(ynl_b + irow*64 + quad*8);
  bf16x8 blf1 = *(const bf16x8*)(ynl_b + irow*64 + 32 + quad*8);
  float sqi = sq_b[irow];

  float d7[7]; int x7[7];
  #pragma unroll
  for (int k = 0; k < 7; ++k) { d7[k] = 3.0e38f; x7[k] = 0x7fffffff; }

  int srow = tid >> 3, oct = tid & 7;    // staging coords

  { // stage chunk 0 into buf 0
    int jt = jbase;
    *(uint4*)&Bh[0][srow*72 + oct*8]      = *(const uint4*)(ynh_b + (jt + srow)*64 + oct*8);
    *(uint4*)&Bh[0][(srow+32)*72 + oct*8] = *(const uint4*)(ynh_b + (jt + srow + 32)*64 + oct*8);
    *(uint4*)&Bl[0][srow*72 + oct*8]      = *(const uint4*)(ynl_b + (jt + srow)*64 + oct*8);
    *(uint4*)&Bl[0][(srow+32)*72 + oct*8] = *(const uint4*)(ynl_b + (jt + srow + 32)*64 + oct*8);
    if (tid < 64) sqjs[0][tid] = sq_b[jt + tid];
  }
  __syncthreads();

  #pragma unroll 1
  for (int c = 0; c < 8; ++c) {
    int buf = c & 1, nbuf = buf ^ 1;
    // prefetch next chunk into registers (overlaps with compute)
    uint4 gh0, gh1, gl0, gl1; float gsq = 0.f;
    if (c < 7) {
      int jt = jbase + (c+1)*64;
      gh0 = *(const uint4*)(ynh_b + (jt + srow)*64 + oct*8);
      gh1 = *(const uint4*)(ynh_b + (jt + srow + 32)*64 + oct*8);
      gl0 = *(const uint4*)(ynl_b + (jt + srow)*64 + oct*8);
      gl1 = *(const uint4*)(ynl_b + (jt + srow + 32)*64 + oct*8);
      if (tid < 64) gsq = sq_b[jt + tid];
    }
    // compute chunk c from buf
    int jt0 = jbase + c*64;
    #pragma unroll
    for (int jn = 0; jn < 4; ++jn) {
      const int ro = (jn*16 + m)*72 + quad*8;
      bf16x8 ajh0 = *(const bf16x8*)&Bh[buf][ro];
      bf16x8 ajh1 = *(const bf16x8*)&Bh[buf][ro + 32];
      bf16x8 ajl0 = *(const bf16x8*)&Bl[buf][ro];
      bf16x8 ajl1 = *(const bf16x8*)&Bl[buf][ro + 32];
      f32x4 sq4 = *(const f32x4*)&sqjs[buf][jn*16 + quad*4];

      f32x4 a = (f32x4){0.f, 0.f, 0.f, 0.f};
      a = __builtin_amdgcn_mfma_f32_16x16x32_bf16(ajh0, bhf0, a, 0, 0, 0);
      a = __builtin_amdgcn_mfma_f32_16x16x32_bf16(ajl0, bhf0, a, 0, 0, 0);
      a = __builtin_amdgcn_mfma_f32_16x16x32_bf16(ajh0, blf0, a, 0, 0, 0);
      a = __builtin_amdgcn_mfma_f32_16x16x32_bf16(ajh1, bhf1, a, 0, 0, 0);
      a = __builtin_amdgcn_mfma_f32_16x16x32_bf16(ajl1, bhf1, a, 0, 0, 0);
      a = __builtin_amdgcn_mfma_f32_16x16x32_bf16(ajh1, blf1, a, 0, 0, 0);

      float d2[4];
      #pragma unroll
      for (int r = 0; r < 4; ++r) d2[r] = fmaf(-2.f, a[r], sqi + sq4[r]);
      float mn = fminf(fminf(d2[0], d2[1]), fminf(d2[2], d2[3]));
      if (mn < d7[6]) {
        #pragma unroll
        for (int r = 0; r < 4; ++r) {
          float d = d2[r];
          if (d < d7[6]) {                 // strict < : ascending j stable
            int jj = jt0 + jn*16 + quad*4 + r;
            int k = 6;
            #pragma unroll
            for (int t = 5; t >= 0; --t)
              if (d < d7[t]) { d7[t+1] = d7[t]; x7[t+1] = x7[t]; k = t; }
            d7[k] = d; x7[k] = jj;
          }
        }
      }
    }
    // commit prefetched chunk to the other buffer
    if (c < 7) {
      *(uint4*)&Bh[nbuf][srow*72 + oct*8]      = gh0;
      *(uint4*)&Bh[nbuf][(srow+32)*72 + oct*8] = gh1;
      *(uint4*)&Bl[nbuf][srow*72 + oct*8]      = gl0;
      *(uint4*)&Bl[nbuf][(srow+32)*72 + oct*8] = gl1;
      if (tid < 64) sqjs[nbuf][tid] = gsq;
    }
    __syncthreads();
  }

  // merge across the 4 quads of each i-row (alias onto Bh; tie-break by idx)
  float* cd = (float*)&Bh[0][0];   // 64*28*4 = 7168 B <= 9216
  int*   ci = (int*)&Bh[1][0];
  int row = w*16 + m;
  #pragma unroll
  for (int k = 0; k < 7; ++k) {
    cd[row*28 + quad*7 + k] = d7[k];
    ci[row*28 + quad*7 + k] = x7[k];
  }
  __syncthreads();
  if (tid < 64) {
    float md[7]; int mi[7];
    #pragma unroll
    for (int k = 0; k < 7; ++k) { md[k] = 3.0e38f; mi[k] = 0x7fffffff; }
    for (int e = 0; e < 28; ++e) {
      float d = cd[tid*28 + e]; int jj = ci[tid*28 + e];
      if (d < md[6] || (d == md[6] && jj < mi[6])) {
        int k = 6;
        #pragma unroll
        for (int t = 5; t >= 0; --t)
          if (d < md[t] || (d == md[t] && jj < mi[t])) { md[t+1] = md[t]; mi[t+1] = mi[t]; k = t; }
        md[k] = d; mi[k] = jj;
      }
    }
    int g = b*NN + i0 + tid;
    int base = (g*NCH + jsp)*7;
    #pragma unroll
    for (int k = 0; k < 7; ++k) { pd[base+k] = md[k]; pidx[base+k] = mi[k]; }
  }
}

// ---------------- K3: merge per-split top7 -> final 7 neighbors --------------
__global__ __launch_bounds__(256) void k_merge(const float* __restrict__ pd,
                                               const int* __restrict__ pidx,
                                               int* __restrict__ nbr) {
  int g = blockIdx.x*256 + threadIdx.x;
  float d7[7]; int x7[7];
  #pragma unroll
  for (int k = 0; k < 7; ++k) { d7[k] = 3.0e38f; x7[k] = 0x7fffffff; }
  int base = g*NCH*7;
  for (int e = 0; e < NCH*7; ++e) {
    float d = pd[base+e]; int jj = pidx[base+e];
    if (d < d7[6]) {
      int k = 6;
      #pragma unroll
      for (int t = 5; t >= 0; --t) {
        if (d < d7[t]) { d7[t+1] = d7[t]; x7[t+1] = x7[t]; k = t; }
      }
      d7[k] = d; x7[k] = jj;
    }
  }
  #pragma unroll
  for (int k = 0; k < 7; ++k) nbr[g*7 + k] = x7[k];
}

// ---------------- K4: hcat = yn @ [W0|W1] + fused f-vectors (reg-W) ---------
__global__ __launch_bounds__(256) void k_hcat(const float* __restrict__ yn,
                                              const float* __restrict__ W0,
                                              const float* __restrict__ W1,
                                              const float* __restrict__ a0,
                                              const float* __restrict__ a1,
                                              float* __restrict__ hcat,
                                              float* __restrict__ fv) {
  __shared__ __align__(16) float yt[16*64];
  int b = blockIdx.x >> 8, n0 = (blockIdx.x & 255)*16;
  int tid = threadIdx.x;
  int c = tid & 127, ng = tid >> 7, lane = tid & 63;
  // this thread's W column in registers
  float wreg[64];
  {
    const float* Wp = (c < 64) ? (W0 + c) : (W1 + (c - 64));
    #pragma unroll
    for (int k = 0; k < 64; ++k) wreg[k] = Wp[k*64];
  }
  ((float4*)yt)[tid] = ((const float4*)(yn + (b*NN + n0)*64))[tid];
  __syncthreads();
  int head = c >> 6;
  float av1 = head ? a1[lane] : a0[lane];
  float av2 = head ? a1[64 + lane] : a0[64 + lane];
  for (int nn = 0; nn < 8; ++nn) {
    int node = ng*8 + nn;
    const float* yr = yt + node*64;
    float acc = 0.f;
    #pragma unroll
    for (int k4 = 0; k4 < 16; ++k4) {
      float4 yv = *(const float4*)(yr + k4*4);
      acc = fmaf(yv.x, wreg[k4*4+0], acc);
      acc = fmaf(yv.y, wreg[k4*4+1], acc);
      acc = fmaf(yv.z, wreg[k4*4+2], acc);
      acc = fmaf(yv.w, wreg[k4*4+3], acc);
    }
    hcat[(b*NN + n0 + node)*128 + c] = acc;
    float s1 = acc*av1, s2 = acc*av2;
    #pragma unroll
    for (int off = 32; off > 0; off >>= 1) {
      s1 += __shfl_xor(s1, off); s2 += __shfl_xor(s2, off);
    }
    if (lane == 0) {
      int gg = (b << 12) + n0 + node;
      fv[head*16384 + gg] = s1;
      fv[head*16384 + 8192 + gg] = s2;
    }
  }
}

// ---------------- K6: GAT layer1 aggregation (2 heads) + relu ---------------
__global__ __launch_bounds__(256) void k_agg1(const float* __restrict__ hcat,
                                              const float* __restrict__ fv,
                                              const int* __restrict__ nbr,
                                              float* __restrict__ hagg) {
  int g = blockIdx.x*2 + (threadIdx.x >> 7);
  int c = threadIdx.x & 127;
  int b = g >> 12;
  int head = c >> 6;
  int jj[7];
  #pragma unroll
  for (int t = 0; t < 7; ++t) jj[t] = nbr[g*7 + t];
  float f1 = fv[head*16384 + g];
  const float* f2p = fv + head*16384 + 8192 + (b << 12);
  float e[7], mx = -3.0e38f;
  #pragma unroll
  for (int t = 0; t < 7; ++t) {
    float v = f1 + f2p[jj[t]];
    v = (v >= 0.f) ? v : 0.2f*v;
    e[t] = v; mx = fmaxf(mx, v);
  }
  float wgt[7], s = 0.f;
  #pragma unroll
  for (int t = 0; t < 7; ++t) { wgt[t] = expf(e[t] - mx); s += wgt[t]; }
  float acc = 0.f;
  #pragma unroll
  for (int t = 0; t < 7; ++t)
    acc += (wgt[t]/s) * hcat[((b << 12) + jj[t])*128 + c];
  hagg[g*128 + c] = fmaxf(acc, 0.f);
}

// ---------------- K7: ho = hagg @ W_out + fused f-vectors (reg-W halves) ----
__global__ __launch_bounds__(256) void k_ho(const float* __restrict__ hagg,
                                            const float* __restrict__ Wout,
                                            const float* __restrict__ aout,
                                            float* __restrict__ ho,
                                            float* __restrict__ fo) {
  __shared__ __align__(16) float ht[16*128];   // 8 KB
  __shared__ float part[16][64];               // 4 KB: k-half-0 partials
  int b = blockIdx.x >> 8, n0 = (blockIdx.x & 255)*16;
  int tid = threadIdx.x;
  int c = tid & 63, g = (tid >> 6) & 1, ng = tid >> 7;
  float wreg[64];
  #pragma unroll
  for (int k = 0; k < 64; ++k) wreg[k] = Wout[(g*64 + k)*64 + c];
  {
    const float4* src = (const float4*)(hagg + (b*NN + n0)*128);
    ((float4*)ht)[tid] = src[tid];
    ((float4*)ht)[tid + 256] = src[tid + 256];
  }
  __syncthreads();
  float accs[8];
  for (int nn = 0; nn < 8; ++nn) {
    int node = ng*8 + nn;
    const float* hr = ht + node*128 + g*64;
    float acc = 0.f;
    #pragma unroll
    for (int k4 = 0; k4 < 16; ++k4) {
      float4 hv = *(const float4*)(hr + k4*4);
      acc = fmaf(hv.x, wreg[k4*4+0], acc);
      acc = fmaf(hv.y, wreg[k4*4+1], acc);
      acc = fmaf(hv.z, wreg[k4*4+2], acc);
      acc = fmaf(hv.w, wreg[k4*4+3], acc);
    }
    accs[nn] = acc;
  }
  if (g == 0) {
    #pragma unroll
    for (int nn = 0; nn < 8; ++nn) part[ng*8 + nn][c] = accs[nn];
  }
  __syncthreads();
  if (g == 1) {
    float av1 = aout[c], av2 = aout[64 + c];
    for (int nn = 0; nn < 8; ++nn) {
      int node = ng*8 + nn;
      float acc = accs[nn] + part[node][c];
      ho[(b*NN + n0 + node)*64 + c] = acc;
      float s1 = acc*av1, s2 = acc*av2;
      #pragma unroll
      for (int off = 32; off > 0; off >>= 1) {
        s1 += __shfl_xor(s1, off); s2 += __shfl_xor(s2, off);
      }
      if (c == 0) {
        int gg = (b << 12) + n0 + node;
        fo[gg] = s1;
        fo[8192 + gg] = s2;
      }
    }
  }
}

// ---------------- K9: layer2 agg + elu + log_softmax ------------------------
__global__ __launch_bounds__(256) void k_agg2(const float* __restrict__ ho,
                                              const float* __restrict__ fo,
                                              const int* __restrict__ nbr,
                                              float* __restrict__ zbuf) {
  int g = blockIdx.x*4 + (threadIdx.x >> 6);
  int c = threadIdx.x & 63;
  int b = g >> 12;
  int jj[7];
  #pragma unroll
  for (int t = 0; t < 7; ++t) jj[t] = nbr[g*7 + t];
  float f1 = fo[g];
  const float* f2p = fo + 8192 + (b << 12);
  float e[7], mx = -3.0e38f;
  #pragma unroll
  for (int t = 0; t < 7; ++t) {
    float v = f1 + f2p[jj[t]];
    v = (v >= 0.f) ? v : 0.2f*v;
    e[t] = v; mx = fmaxf(mx, v);
  }
  float wgt[7], s = 0.f;
  #pragma unroll
  for (int t = 0; t < 7; ++t) { wgt[t] = expf(e[t] - mx); s += wgt[t]; }
  float acc = 0.f;
  #pragma unroll
  for (int t = 0; t < 7; ++t)
    acc += (wgt[t]/s) * ho[((b << 12) + jj[t])*64 + c];
  float v = (acc > 0.f) ? acc : expm1f(acc);
  float mm = v;
  #pragma unroll
  for (int off = 32; off > 0; off >>= 1) mm = fmaxf(mm, __shfl_xor(mm, off));
  float ex = expf(v - mm), ss = ex;
  #pragma unroll
  for (int off = 32; off > 0; off >>= 1) ss += __shfl_xor(ss, off);
  zbuf[g*64 + c] = v - mm - logf(ss);
}

// ---------------- K10: ConvTranspose2d v2 — per-row tap-looped LDS matmul ---
__global__ __launch_bounds__(256) void k_convt2(const float* __restrict__ z,
                                                const float* __restrict__ wT,
                                                const float* __restrict__ bias,
                                                float* __restrict__ out) {
  __shared__ __align__(16) float lds[12800];   // 51200 B
  float* zt = lds;              // [2 rows][64 ci][68]
  float* ws = lds + 8704;       // [64 ci][64 co]
  float* so = lds;              // [64 co][129] epilogue alias

  int oy = blockIdx.x, b = blockIdx.y;
  int r = oy >> 1, pi = oy & 1;
  int tid = threadIdx.x;
  int colo = tid & 15, pgrp = tid >> 4;
  int co4 = colo*4, m0 = pgrp*4;

  int nrows = pi ? 2 : 1;
  for (int row = 0; row < nrows; ++row) {
    int iy = r + row;
    const float* zsrc = z + (((b << 12) + iy*64) << 6);
    for (int idx = tid; idx < 4352; idx += 256) {
      int ix = idx >> 6, ci = idx & 63;
      float v = 0.f;
      if (ix < 64 && iy < 64) v = zsrc[ix*64 + ci];
      zt[row*4352 + ci*68 + ix] = v;
    }
  }

  float acc[2][4][4];
  {
    float4 bv = *(const float4*)&bias[co4];
    #pragma unroll
    for (int chi = 0; chi < 2; ++chi)
      #pragma unroll
      for (int k = 0; k < 4; ++k) {
        acc[chi][k][0] = bv.x; acc[chi][k][1] = bv.y;
        acc[chi][k][2] = bv.z; acc[chi][k][3] = bv.w;
      }
  }

  int kys[2], rows[2], nky;
  if (pi == 0) { kys[0] = 1; rows[0] = 0; nky = 1; }
  else         { kys[0] = 2; rows[0] = 0; kys[1] = 0; rows[1] = 1; nky = 2; }

  for (int t = 0; t < nky; ++t) {
    const float* zrow = zt + rows[t]*4352;
    for (int kx = 0; kx < 3; ++kx) {
      const float* wsrc = wT + (kys[t]*3 + kx)*4096;
      __syncthreads();
      for (int idx = tid; idx < 4096; idx += 256) ws[idx] = wsrc[idx];
      __syncthreads();
      int chi = (kx == 1) ? 0 : 1;
      int xoff = (kx == 0) ? 1 : 0;
      float* ap = &acc[chi][0][0];
      for (int ci = 0; ci < 64; ++ci) {
        float4 wv = *(const float4*)&ws[ci*64 + co4];
        const float* zp = zrow + ci*68 + m0;
        float4 zv;
        if (xoff == 0) {
          zv = *(const float4*)zp;
        } else {
          float4 a0 = *(const float4*)zp;
          float4 a1 = *(const float4*)(zp + 4);
          zv.x = a0.y; zv.y = a0.z; zv.z = a0.w; zv.w = a1.x;
        }
        #pragma unroll
        for (int k = 0; k < 4; ++k) {
          float zk = (&zv.x)[k];
          ap[k*4+0] += zk * wv.x;
          ap[k*4+1] += zk * wv.y;
          ap[k*4+2] += zk * wv.z;
          ap[k*4+3] += zk * wv.w;
        }
      }
    }
  }

  __syncthreads();
  #pragma unroll
  for (int chi = 0; chi < 2; ++chi)
    #pragma unroll
    for (int k = 0; k < 4; ++k)
      #pragma unroll
      for (int cc = 0; cc < 4; ++cc)
        so[(co4 + cc)*129 + 2*(m0 + k) + chi] = acc[chi][k][cc];
  __syncthreads();
  for (int idx = tid; idx < 8192; idx += 256) {
    int co = idx >> 7, ox = idx & 127;
    out[(((b << 6) + co)*128 + oy)*128 + ox] = so[co*129 + ox];
  }
}

// ---------------- launch ----------------------------------------------------
extern "C" void kernel_launch(void* const* d_in, const int* in_sizes, int n_in,
                              void* d_out, int out_size, void* d_ws, size_t ws_size,
                              hipStream_t stream) {
  const float* x      = (const float*)d_in[0];
  const float* w_head = (const float*)d_in[1];
  const float* b_head = (const float*)d_in[2];
  const float* W0     = (const float*)d_in[3];
  const float* a0     = (const float*)d_in[4];
  const float* W1     = (const float*)d_in[5];
  const float* a1     = (const float*)d_in[6];
  const float* W_out  = (const float*)d_in[7];
  const float* a_out  = (const float*)d_in[8];
  const float* w_last = (const float*)d_in[9];
  const float* b_last = (const float*)d_in[10];
  float* out = (float*)d_out;

  float* wsf = (float*)d_ws;
  int*   wsi = (int*)d_ws;
  float* yn   = wsf + OF_YN;
  float* sq   = wsf + OF_SQ;
  float* hcat = wsf + OF_HCAT;
  float* fv   = wsf + OF_FV;
  float* hagg = wsf + OF_HAGG;
  float* ho   = wsf + OF_HO;
  float* fo   = wsf + OF_FO;
  float* zbuf = wsf + OF_Z;
  float* pd   = wsf + OF_PD;
  int*   pidx = wsi + OF_PI;
  int*   nbr  = wsi + OF_NBR;
  float* wT   = wsf + OF_WT;
  float* whT  = wsf + OF_WHT;
  unsigned short* ynh = (unsigned short*)(wsf + OF_YNH);
  unsigned short* ynl = (unsigned short*)(wsf + OF_YNL);

  hipLaunchKernelGGL(k_prep,  dim3(214), dim3(256), 0, stream, w_last, w_head, wT, whT);
  hipLaunchKernelGGL(k_head,  dim3(256), dim3(256), 0, stream, x, whT, b_head, yn, sq, ynh, ynl);
  hipLaunchKernelGGL(k_knn5,  dim3(64, NCH, 2), dim3(256), 0, stream, ynh, ynl, sq, pd, pidx);
  hipLaunchKernelGGL(k_merge, dim3(32), dim3(256), 0, stream, pd, pidx, nbr);
  hipLaunchKernelGGL(k_hcat,  dim3(512), dim3(256), 0, stream, yn, W0, W1, a0, a1, hcat, fv);
  hipLaunchKernelGGL(k_agg1,  dim3(4096), dim3(256), 0, stream, hcat, fv, nbr, hagg);
  hipLaunchKernelGGL(k_ho,    dim3(512), dim3(256), 0, stream, hagg, W_out, a_out, ho, fo);
  hipLaunchKernelGGL(k_agg2,  dim3(2048), dim3(256), 0, stream, ho, fo, nbr, zbuf);
  hipLaunchKernelGGL(k_convt2, dim3(128, 2), dim3(256), 0, stream, zbuf, wT, b_last, out);
}

// Round 7
// 256.776 us; speedup vs baseline: 1.1017x; 1.0536x over previous
//
#include <hip/hip_runtime.h>
#include <math.h>

// Problem constants
#define B2     2
#define CIN    31
#define CC     64      // conv out channels / GAT dim
#define NN     4096    // 64*64 nodes
#define NCH    8       // kNN j-splits (512 j each)

typedef short bf16x8 __attribute__((ext_vector_type(8)));
typedef float f32x4  __attribute__((ext_vector_type(4)));

__device__ inline unsigned short f2bf(float f) {
  union { float f; unsigned u; } v; v.f = f;
  unsigned r = (v.u + 0x7fffu + ((v.u >> 16) & 1u)) >> 16;
  return (unsigned short)r;
}
__device__ inline float bf2f(unsigned short h) {
  union { float f; unsigned u; } v; v.u = ((unsigned)h) << 16;
  return v.f;
}

// ---------------- workspace layout (in 4-byte elements) ----------------
constexpr int OF_YN   = 0;                         // [B,N,64] fp32
constexpr int OF_SQ   = OF_YN   + B2*NN*CC;        // [B,N]
constexpr int OF_HCAT = OF_SQ   + B2*NN;           // [B,N,128]
constexpr int OF_FV   = OF_HCAT + B2*NN*128;       // 4 x [B*N]
constexpr int OF_HAGG = OF_FV   + 4*B2*NN;         // [B,N,128]
constexpr int OF_HO   = OF_HAGG + B2*NN*128;       // [B,N,64]
constexpr int OF_FO   = OF_HO   + B2*NN*CC;        // 2 x [B*N]
constexpr int OF_Z    = OF_FO   + 2*B2*NN;         // [B,N,64]
constexpr int OF_PD   = OF_Z    + B2*NN*CC;        // partial top7 dists [B*N][NCH][7]
constexpr int OF_PI   = OF_PD   + B2*NN*NCH*7;     // partial top7 idx (int)
constexpr int OF_NBR  = OF_PI   + B2*NN*NCH*7;     // [B*N][7] neighbor idx (int)
constexpr int OF_WT   = OF_NBR  + B2*NN*7;         // convT weights [9][64][64]
constexpr int OF_WHT  = OF_WT   + 9*64*64;         // head conv weights [279][64]
constexpr int OF_YNH  = OF_WHT  + 279*64;          // bf16 hi [B,N,64] (ushort)
constexpr int OF_YNL  = OF_YNH  + B2*NN*CC/2;      // bf16 lo [B,N,64] (ushort)

// ---------------- K0: weight transposes ----------------
__global__ __launch_bounds__(256) void k_prep(const float* __restrict__ wlast,
                                              const float* __restrict__ whead,
                                              float* __restrict__ wT,
                                              float* __restrict__ whT) {
  int idx = blockIdx.x*256 + threadIdx.x;
  if (idx < 36864) {
    int co = idx & 63, ci = (idx >> 6) & 63, kk = idx >> 12;
    wT[idx] = wlast[(ci*64 + co)*9 + kk];
  } else if (idx < 36864 + 279*64) {
    int j = idx - 36864;
    int c = j & 63, q = j >> 6;
    whT[j] = whead[c*279 + q];
  }
}

// ---------------- K1: head conv + sq + bf16 split (1024 blocks, 4/CU) -------
__global__ __launch_bounds__(256) void k_head(const float* __restrict__ x,
                                              const float* __restrict__ whT,
                                              const float* __restrict__ bias,
                                              float* __restrict__ yn,
                                              float* __restrict__ sq,
                                              unsigned short* __restrict__ ynh,
                                              unsigned short* __restrict__ ynl) {
  int lane = threadIdx.x & 63, wv = threadIdx.x >> 6;
  int gbase = blockIdx.x*8 + wv*2;               // 2 nodes per wave
  __shared__ __align__(16) float patch[4][2][280];
  for (int nn = 0; nn < 2; ++nn) {
    int g = gbase + nn;
    int b = g >> 12, n = g & 4095;
    int oh = n >> 6, ow = n & 63;
    for (int q = lane; q < 279; q += 64) {
      int ci = q / 9, r = q - ci*9;
      int ky = r / 3, kx = r - ky*3;
      int ih = 2*oh - 1 + ky, iw = 2*ow - 1 + kx;
      float v = 0.f;
      if (ih >= 0 && ih < 128 && iw >= 0 && iw < 128)
        v = x[((b*CIN + ci)*128 + ih)*128 + iw];
      patch[wv][nn][q] = v;
    }
  }
  __syncthreads();
  int c = lane;
  float acc[2];
  float bv = bias[c];
  acc[0] = bv; acc[1] = bv;
  for (int q = 0; q < 276; q += 4) {
    float w0 = whT[q*64 + c];
    float w1 = whT[(q+1)*64 + c];
    float w2 = whT[(q+2)*64 + c];
    float w3 = whT[(q+3)*64 + c];
    #pragma unroll
    for (int nn = 0; nn < 2; ++nn) {
      float4 pv = *(const float4*)&patch[wv][nn][q];
      acc[nn] = fmaf(pv.x, w0, acc[nn]);
      acc[nn] = fmaf(pv.y, w1, acc[nn]);
      acc[nn] = fmaf(pv.z, w2, acc[nn]);
      acc[nn] = fmaf(pv.w, w3, acc[nn]);
    }
  }
  for (int q = 276; q < 279; ++q) {
    float wq = whT[q*64 + c];
    #pragma unroll
    for (int nn = 0; nn < 2; ++nn) acc[nn] = fmaf(patch[wv][nn][q], wq, acc[nn]);
  }
  for (int nn = 0; nn < 2; ++nn) {
    int g = gbase + nn;
    float y = acc[nn];
    yn[g*64 + c] = y;
    unsigned short hb = f2bf(y);
    ynh[g*64 + c] = hb;
    ynl[g*64 + c] = f2bf(y - bf2f(hb));
    float s = y*y;
    #pragma unroll
    for (int off = 32; off > 0; off >>= 1) s += __shfl_xor(s, off);
    if (lane == 0) sq[g] = s;
  }
}

// ---------------- K2: LDS-staged (dbuf) MFMA Gram + in-register top-7 -------
__global__ __launch_bounds__(256, 4) void k_knn5(const unsigned short* __restrict__ ynh,
                                                 const unsigned short* __restrict__ ynl,
                                                 const float* __restrict__ sq,
                                                 float* __restrict__ pd,
                                                 int* __restrict__ pidx) {
  __shared__ __align__(16) unsigned short Bh[2][64*72];
  __shared__ __align__(16) unsigned short Bl[2][64*72];
  __shared__ __align__(16) float sqjs[2][64];

  int b = blockIdx.z, ib = blockIdx.x, jsp = blockIdx.y;
  int i0 = ib*64, jbase = jsp*512;
  int tid = threadIdx.x;
  int lane = tid & 63, w = tid >> 6;
  int quad = lane >> 4, m = lane & 15;

  const unsigned short* ynh_b = ynh + (size_t)b*NN*64;
  const unsigned short* ynl_b = ynl + (size_t)b*NN*64;
  const float* sq_b = sq + b*NN;

  int irow = i0 + w*16 + m;
  bf16x8 bhf0 = *(const bf16x8*)(ynh_b + irow*64 + quad*8);
  bf16x8 bhf1 = *(const bf16x8*)(ynh_b + irow*64 + 32 + quad*8);
  bf16x8 blf0 = *(const bf16x8*)(ynl_b + irow*64 + quad*8);
  bf16x8 blf1 = *(const bf16x8*)(ynl_b + irow*64 + 32 + quad*8);
  float sqi = sq_b[irow];

  float d7[7]; int x7[7];
  #pragma unroll
  for (int k = 0; k < 7; ++k) { d7[k] = 3.0e38f; x7[k] = 0x7fffffff; }

  int srow = tid >> 3, oct = tid & 7;

  {
    int jt = jbase;
    *(uint4*)&Bh[0][srow*72 + oct*8]      = *(const uint4*)(ynh_b + (jt + srow)*64 + oct*8);
    *(uint4*)&Bh[0][(srow+32)*72 + oct*8] = *(const uint4*)(ynh_b + (jt + srow + 32)*64 + oct*8);
    *(uint4*)&Bl[0][srow*72 + oct*8]      = *(const uint4*)(ynl_b + (jt + srow)*64 + oct*8);
    *(uint4*)&Bl[0][(srow+32)*72 + oct*8] = *(const uint4*)(ynl_b + (jt + srow + 32)*64 + oct*8);
    if (tid < 64) sqjs[0][tid] = sq_b[jt + tid];
  }
  __syncthreads();

  #pragma unroll 1
  for (int c = 0; c < 8; ++c) {
    int buf = c & 1, nbuf = buf ^ 1;
    uint4 gh0, gh1, gl0, gl1; float gsq = 0.f;
    if (c < 7) {
      int jt = jbase + (c+1)*64;
      gh0 = *(const uint4*)(ynh_b + (jt + srow)*64 + oct*8);
      gh1 = *(const uint4*)(ynh_b + (jt + srow + 32)*64 + oct*8);
      gl0 = *(const uint4*)(ynl_b + (jt + srow)*64 + oct*8);
      gl1 = *(const uint4*)(ynl_b + (jt + srow + 32)*64 + oct*8);
      if (tid < 64) gsq = sq_b[jt + tid];
    }
    int jt0 = jbase + c*64;
    #pragma unroll
    for (int jn = 0; jn < 4; ++jn) {
      const int ro = (jn*16 + m)*72 + quad*8;
      bf16x8 ajh0 = *(const bf16x8*)&Bh[buf][ro];
      bf16x8 ajh1 = *(const bf16x8*)&Bh[buf][ro + 32];
      bf16x8 ajl0 = *(const bf16x8*)&Bl[buf][ro];
      bf16x8 ajl1 = *(const bf16x8*)&Bl[buf][ro + 32];
      f32x4 sq4 = *(const f32x4*)&sqjs[buf][jn*16 + quad*4];

      f32x4 a = (f32x4){0.f, 0.f, 0.f, 0.f};
      a = __builtin_amdgcn_mfma_f32_16x16x32_bf16(ajh0, bhf0, a, 0, 0, 0);
      a = __builtin_amdgcn_mfma_f32_16x16x32_bf16(ajl0, bhf0, a, 0, 0, 0);
      a = __builtin_amdgcn_mfma_f32_16x16x32_bf16(ajh0, blf0, a, 0, 0, 0);
      a = __builtin_amdgcn_mfma_f32_16x16x32_bf16(ajh1, bhf1, a, 0, 0, 0);
      a = __builtin_amdgcn_mfma_f32_16x16x32_bf16(ajl1, bhf1, a, 0, 0, 0);
      a = __builtin_amdgcn_mfma_f32_16x16x32_bf16(ajh1, blf1, a, 0, 0, 0);

      float d2[4];
      #pragma unroll
      for (int r = 0; r < 4; ++r) d2[r] = fmaf(-2.f, a[r], sqi + sq4[r]);
      float mn = fminf(fminf(d2[0], d2[1]), fminf(d2[2], d2[3]));
      if (mn < d7[6]) {
        #pragma unroll
        for (int r = 0; r < 4; ++r) {
          float d = d2[r];
          if (d < d7[6]) {                 // strict < : ascending j stable
            int jj = jt0 + jn*16 + quad*4 + r;
            int k = 6;
            #pragma unroll
            for (int t = 5; t >= 0; --t)
              if (d < d7[t]) { d7[t+1] = d7[t]; x7[t+1] = x7[t]; k = t; }
            d7[k] = d; x7[k] = jj;
          }
        }
      }
    }
    if (c < 7) {
      *(uint4*)&Bh[nbuf][srow*72 + oct*8]      = gh0;
      *(uint4*)&Bh[nbuf][(srow+32)*72 + oct*8] = gh1;
      *(uint4*)&Bl[nbuf][srow*72 + oct*8]      = gl0;
      *(uint4*)&Bl[nbuf][(srow+32)*72 + oct*8] = gl1;
      if (tid < 64) sqjs[nbuf][tid] = gsq;
    }
    __syncthreads();
  }

  float* cd = (float*)&Bh[0][0];
  int*   ci = (int*)&Bh[1][0];
  int row = w*16 + m;
  #pragma unroll
  for (int k = 0; k < 7; ++k) {
    cd[row*28 + quad*7 + k] = d7[k];
    ci[row*28 + quad*7 + k] = x7[k];
  }
  __syncthreads();
  if (tid < 64) {
    float md[7]; int mi[7];
    #pragma unroll
    for (int k = 0; k < 7; ++k) { md[k] = 3.0e38f; mi[k] = 0x7fffffff; }
    for (int e = 0; e < 28; ++e) {
      float d = cd[tid*28 + e]; int jj = ci[tid*28 + e];
      if (d < md[6] || (d == md[6] && jj < mi[6])) {
        int k = 6;
        #pragma unroll
        for (int t = 5; t >= 0; --t)
          if (d < md[t] || (d == md[t] && jj < mi[t])) { md[t+1] = md[t]; mi[t+1] = mi[t]; k = t; }
        md[k] = d; mi[k] = jj;
      }
    }
    int g = b*NN + i0 + tid;
    int base = (g*NCH + jsp)*7;
    #pragma unroll
    for (int k = 0; k < 7; ++k) { pd[base+k] = md[k]; pidx[base+k] = mi[k]; }
  }
}

// ---------------- K4: fused [hcat GEMM + f-vectors] and [top7 merge] --------
// blocks 0..511: hcat path; blocks 512..543: merge path.
__global__ __launch_bounds__(256) void k_hm(const float* __restrict__ yn,
                                            const float* __restrict__ W0,
                                            const float* __restrict__ W1,
                                            const float* __restrict__ a0,
                                            const float* __restrict__ a1,
                                            float* __restrict__ hcat,
                                            float* __restrict__ fv,
                                            const float* __restrict__ pd,
                                            const int* __restrict__ pidx,
                                            int* __restrict__ nbr) {
  __shared__ __align__(16) float yt[16*64];
  int tid = threadIdx.x;
  if (blockIdx.x >= 512) {
    // ---- merge path ----
    int g = (blockIdx.x - 512)*256 + tid;    // 0..8191
    float d7[7]; int x7[7];
    #pragma unroll
    for (int k = 0; k < 7; ++k) { d7[k] = 3.0e38f; x7[k] = 0x7fffffff; }
    int base = g*NCH*7;
    for (int e = 0; e < NCH*7; ++e) {
      float d = pd[base+e]; int jj = pidx[base+e];
      if (d < d7[6]) {
        int k = 6;
        #pragma unroll
        for (int t = 5; t >= 0; --t) {
          if (d < d7[t]) { d7[t+1] = d7[t]; x7[t+1] = x7[t]; k = t; }
        }
        d7[k] = d; x7[k] = jj;
      }
    }
    #pragma unroll
    for (int k = 0; k < 7; ++k) nbr[g*7 + k] = x7[k];
    return;
  }
  // ---- hcat path ----
  int b = blockIdx.x >> 8, n0 = (blockIdx.x & 255)*16;
  int c = tid & 127, ng = tid >> 7, lane = tid & 63;
  float wreg[64];
  {
    const float* Wp = (c < 64) ? (W0 + c) : (W1 + (c - 64));
    #pragma unroll
    for (int k = 0; k < 64; ++k) wreg[k] = Wp[k*64];
  }
  ((float4*)yt)[tid] = ((const float4*)(yn + (b*NN + n0)*64))[tid];
  __syncthreads();
  int head = c >> 6;
  float av1 = head ? a1[lane] : a0[lane];
  float av2 = head ? a1[64 + lane] : a0[64 + lane];
  for (int nn = 0; nn < 8; ++nn) {
    int node = ng*8 + nn;
    const float* yr = yt + node*64;
    float acc = 0.f;
    #pragma unroll
    for (int k4 = 0; k4 < 16; ++k4) {
      float4 yv = *(const float4*)(yr + k4*4);
      acc = fmaf(yv.x, wreg[k4*4+0], acc);
      acc = fmaf(yv.y, wreg[k4*4+1], acc);
      acc = fmaf(yv.z, wreg[k4*4+2], acc);
      acc = fmaf(yv.w, wreg[k4*4+3], acc);
    }
    hcat[(b*NN + n0 + node)*128 + c] = acc;
    float s1 = acc*av1, s2 = acc*av2;
    #pragma unroll
    for (int off = 32; off > 0; off >>= 1) {
      s1 += __shfl_xor(s1, off); s2 += __shfl_xor(s2, off);
    }
    if (lane == 0) {
      int gg = (b << 12) + n0 + node;
      fv[head*16384 + gg] = s1;
      fv[head*16384 + 8192 + gg] = s2;
    }
  }
}

// ---------------- K6: GAT layer1 aggregation (2 heads) + relu ---------------
__global__ __launch_bounds__(256) void k_agg1(const float* __restrict__ hcat,
                                              const float* __restrict__ fv,
                                              const int* __restrict__ nbr,
                                              float* __restrict__ hagg) {
  int g = blockIdx.x*2 + (threadIdx.x >> 7);
  int c = threadIdx.x & 127;
  int b = g >> 12;
  int head = c >> 6;
  int jj[7];
  #pragma unroll
  for (int t = 0; t < 7; ++t) jj[t] = nbr[g*7 + t];
  float f1 = fv[head*16384 + g];
  const float* f2p = fv + head*16384 + 8192 + (b << 12);
  float e[7], mx = -3.0e38f;
  #pragma unroll
  for (int t = 0; t < 7; ++t) {
    float v = f1 + f2p[jj[t]];
    v = (v >= 0.f) ? v : 0.2f*v;
    e[t] = v; mx = fmaxf(mx, v);
  }
  float wgt[7], s = 0.f;
  #pragma unroll
  for (int t = 0; t < 7; ++t) { wgt[t] = expf(e[t] - mx); s += wgt[t]; }
  float acc = 0.f;
  #pragma unroll
  for (int t = 0; t < 7; ++t)
    acc += (wgt[t]/s) * hcat[((b << 12) + jj[t])*128 + c];
  hagg[g*128 + c] = fmaxf(acc, 0.f);
}

// ---------------- K7: ho = hagg @ W_out + fused f-vectors (reg-W halves) ----
__global__ __launch_bounds__(256) void k_ho(const float* __restrict__ hagg,
                                            const float* __restrict__ Wout,
                                            const float* __restrict__ aout,
                                            float* __restrict__ ho,
                                            float* __restrict__ fo) {
  __shared__ __align__(16) float ht[16*128];
  __shared__ float part[16][64];
  int b = blockIdx.x >> 8, n0 = (blockIdx.x & 255)*16;
  int tid = threadIdx.x;
  int c = tid & 63, g = (tid >> 6) & 1, ng = tid >> 7;
  float wreg[64];
  #pragma unroll
  for (int k = 0; k < 64; ++k) wreg[k] = Wout[(g*64 + k)*64 + c];
  {
    const float4* src = (const float4*)(hagg + (b*NN + n0)*128);
    ((float4*)ht)[tid] = src[tid];
    ((float4*)ht)[tid + 256] = src[tid + 256];
  }
  __syncthreads();
  float accs[8];
  for (int nn = 0; nn < 8; ++nn) {
    int node = ng*8 + nn;
    const float* hr = ht + node*128 + g*64;
    float acc = 0.f;
    #pragma unroll
    for (int k4 = 0; k4 < 16; ++k4) {
      float4 hv = *(const float4*)(hr + k4*4);
      acc = fmaf(hv.x, wreg[k4*4+0], acc);
      acc = fmaf(hv.y, wreg[k4*4+1], acc);
      acc = fmaf(hv.z, wreg[k4*4+2], acc);
      acc = fmaf(hv.w, wreg[k4*4+3], acc);
    }
    accs[nn] = acc;
  }
  if (g == 0) {
    #pragma unroll
    for (int nn = 0; nn < 8; ++nn) part[ng*8 + nn][c] = accs[nn];
  }
  __syncthreads();
  if (g == 1) {
    float av1 = aout[c], av2 = aout[64 + c];
    for (int nn = 0; nn < 8; ++nn) {
      int node = ng*8 + nn;
      float acc = accs[nn] + part[node][c];
      ho[(b*NN + n0 + node)*64 + c] = acc;
      float s1 = acc*av1, s2 = acc*av2;
      #pragma unroll
      for (int off = 32; off > 0; off >>= 1) {
        s1 += __shfl_xor(s1, off); s2 += __shfl_xor(s2, off);
      }
      if (c == 0) {
        int gg = (b << 12) + n0 + node;
        fo[gg] = s1;
        fo[8192 + gg] = s2;
      }
    }
  }
}

// ---------------- K9: layer2 agg + elu + log_softmax ------------------------
__global__ __launch_bounds__(256) void k_agg2(const float* __restrict__ ho,
                                              const float* __restrict__ fo,
                                              const int* __restrict__ nbr,
                                              float* __restrict__ zbuf) {
  int g = blockIdx.x*4 + (threadIdx.x >> 6);
  int c = threadIdx.x & 63;
  int b = g >> 12;
  int jj[7];
  #pragma unroll
  for (int t = 0; t < 7; ++t) jj[t] = nbr[g*7 + t];
  float f1 = fo[g];
  const float* f2p = fo + 8192 + (b << 12);
  float e[7], mx = -3.0e38f;
  #pragma unroll
  for (int t = 0; t < 7; ++t) {
    float v = f1 + f2p[jj[t]];
    v = (v >= 0.f) ? v : 0.2f*v;
    e[t] = v; mx = fmaxf(mx, v);
  }
  float wgt[7], s = 0.f;
  #pragma unroll
  for (int t = 0; t < 7; ++t) { wgt[t] = expf(e[t] - mx); s += wgt[t]; }
  float acc = 0.f;
  #pragma unroll
  for (int t = 0; t < 7; ++t)
    acc += (wgt[t]/s) * ho[((b << 12) + jj[t])*64 + c];
  float v = (acc > 0.f) ? acc : expm1f(acc);
  float mm = v;
  #pragma unroll
  for (int off = 32; off > 0; off >>= 1) mm = fmaxf(mm, __shfl_xor(mm, off));
  float ex = expf(v - mm), ss = ex;
  #pragma unroll
  for (int off = 32; off > 0; off >>= 1) ss += __shfl_xor(ss, off);
  zbuf[g*64 + c] = v - mm - logf(ss);
}

// ---------------- K10: ConvTranspose2d v3 — half-row blocks (512, 2/CU) -----
// grid (128 oy, 2 xh, 2 b), 256 threads. Block computes [64 co][64 ox].
__global__ __launch_bounds__(256) void k_convt3(const float* __restrict__ z,
                                                const float* __restrict__ wT,
                                                const float* __restrict__ bias,
                                                float* __restrict__ out) {
  __shared__ __align__(16) float lds[8704];    // 34816 B
  float* zt = lds;              // [2 rows][64 ci][36]  (4608 floats)
  float* ws = lds + 4608;       // [64 ci][64 co]       (4096 floats)
  float* so = lds;              // [64 co][65] epilogue alias (4160 floats)

  int oy = blockIdx.x, xh = blockIdx.y, b = blockIdx.z;
  int r = oy >> 1, pi = oy & 1;
  int tid = threadIdx.x;
  int colo = tid & 15, pgrp = tid >> 4;
  int co4 = colo*4, m0 = pgrp*2;
  int ix0 = xh*32;

  // stage z slice: ix_global in [ix0, ix0+32], zero-padded OOB
  int nrows = pi ? 2 : 1;
  for (int row = 0; row < nrows; ++row) {
    int iy = r + row;
    const float* zsrc = z + (((b << 12) + iy*64) << 6);
    for (int idx = tid; idx < 2112; idx += 256) {
      int ix = idx >> 6, ci = idx & 63;           // ix in [0,33)
      int ixg = ix0 + ix;
      float v = 0.f;
      if (ixg < 64 && iy < 64) v = zsrc[ixg*64 + ci];
      zt[row*2304 + ci*36 + ix] = v;
    }
  }

  // acc[chi][k][cc]: parity chi, 2 pixels (k), 4 co
  float acc[2][2][4];
  {
    float4 bv = *(const float4*)&bias[co4];
    #pragma unroll
    for (int chi = 0; chi < 2; ++chi)
      #pragma unroll
      for (int k = 0; k < 2; ++k) {
        acc[chi][k][0] = bv.x; acc[chi][k][1] = bv.y;
        acc[chi][k][2] = bv.z; acc[chi][k][3] = bv.w;
      }
  }

  int kys[2], rows[2], nky;
  if (pi == 0) { kys[0] = 1; rows[0] = 0; nky = 1; }
  else         { kys[0] = 2; rows[0] = 0; kys[1] = 0; rows[1] = 1; nky = 2; }

  for (int t = 0; t < nky; ++t) {
    const float* zrow = zt + rows[t]*2304;
    #pragma unroll
    for (int kx = 0; kx < 3; ++kx) {
      const float* wsrc = wT + (kys[t]*3 + kx)*4096;
      __syncthreads();
      for (int idx = tid; idx < 4096; idx += 256) ws[idx] = wsrc[idx];
      __syncthreads();
      const int chi = (kx == 1) ? 0 : 1;
      const int xoff = (kx == 0) ? 1 : 0;
      float* ap = &acc[chi][0][0];
      for (int ci = 0; ci < 64; ++ci) {
        float4 wv = *(const float4*)&ws[ci*64 + co4];
        const float* zp = zrow + ci*36 + m0;
        float z0, z1;
        if (xoff == 0) { float2 za = *(const float2*)zp; z0 = za.x; z1 = za.y; }
        else           { float2 za = *(const float2*)zp; z0 = za.y; z1 = zp[2]; }
        ap[0] = fmaf(z0, wv.x, ap[0]);
        ap[1] = fmaf(z0, wv.y, ap[1]);
        ap[2] = fmaf(z0, wv.z, ap[2]);
        ap[3] = fmaf(z0, wv.w, ap[3]);
        ap[4] = fmaf(z1, wv.x, ap[4]);
        ap[5] = fmaf(z1, wv.y, ap[5]);
        ap[6] = fmaf(z1, wv.z, ap[6]);
        ap[7] = fmaf(z1, wv.w, ap[7]);
      }
    }
  }

  // epilogue: LDS transpose -> coalesced stores (64 co x 64 ox)
  __syncthreads();
  #pragma unroll
  for (int chi = 0; chi < 2; ++chi)
    #pragma unroll
    for (int k = 0; k < 2; ++k)
      #pragma unroll
      for (int cc = 0; cc < 4; ++cc)
        so[(co4 + cc)*65 + 2*(m0 + k) + chi] = acc[chi][k][cc];
  __syncthreads();
  for (int idx = tid; idx < 4096; idx += 256) {
    int co = idx >> 6, ox = idx & 63;
    out[(((b << 6) + co)*128 + oy)*128 + xh*64 + ox] = so[co*65 + ox];
  }
}

// ---------------- launch ----------------------------------------------------
extern "C" void kernel_launch(void* const* d_in, const int* in_sizes, int n_in,
                              void* d_out, int out_size, void* d_ws, size_t ws_size,
                              hipStream_t stream) {
  const float* x      = (const float*)d_in[0];
  const float* w_head = (const float*)d_in[1];
  const float* b_head = (const float*)d_in[2];
  const float* W0     = (const float*)d_in[3];
  const float* a0     = (const float*)d_in[4];
  const float* W1     = (const float*)d_in[5];
  const float* a1     = (const float*)d_in[6];
  const float* W_out  = (const float*)d_in[7];
  const float* a_out  = (const float*)d_in[8];
  const float* w_last = (const float*)d_in[9];
  const float* b_last = (const float*)d_in[10];
  float* out = (float*)d_out;

  float* wsf = (float*)d_ws;
  int*   wsi = (int*)d_ws;
  float* yn   = wsf + OF_YN;
  float* sq   = wsf + OF_SQ;
  float* hcat = wsf + OF_HCAT;
  float* fv   = wsf + OF_FV;
  float* hagg = wsf + OF_HAGG;
  float* ho   = wsf + OF_HO;
  float* fo   = wsf + OF_FO;
  float* zbuf = wsf + OF_Z;
  float* pd   = wsf + OF_PD;
  int*   pidx = wsi + OF_PI;
  int*   nbr  = wsi + OF_NBR;
  float* wT   = wsf + OF_WT;
  float* whT  = wsf + OF_WHT;
  unsigned short* ynh = (unsigned short*)(wsf + OF_YNH);
  unsigned short* ynl = (unsigned short*)(wsf + OF_YNL);

  hipLaunchKernelGGL(k_prep,  dim3(214), dim3(256), 0, stream, w_last, w_head, wT, whT);
  hipLaunchKernelGGL(k_head,  dim3(1024), dim3(256), 0, stream, x, whT, b_head, yn, sq, ynh, ynl);
  hipLaunchKernelGGL(k_knn5,  dim3(64, NCH, 2), dim3(256), 0, stream, ynh, ynl, sq, pd, pidx);
  hipLaunchKernelGGL(k_hm,    dim3(544), dim3(256), 0, stream, yn, W0, W1, a0, a1, hcat, fv, pd, pidx, nbr);
  hipLaunchKernelGGL(k_agg1,  dim3(4096), dim3(256), 0, stream, hcat, fv, nbr, hagg);
  hipLaunchKernelGGL(k_ho,    dim3(512), dim3(256), 0, stream, hagg, W_out, a_out, ho, fo);
  hipLaunchKernelGGL(k_agg2,  dim3(2048), dim3(256), 0, stream, ho, fo, nbr, zbuf);
  hipLaunchKernelGGL(k_convt3, dim3(128, 2, 2), dim3(256), 0, stream, zbuf, wT, b_last, out);
}

// Round 8
// 230.079 us; speedup vs baseline: 1.2296x; 1.1160x over previous
//
#include <hip/hip_runtime.h>
#include <math.h>

// Problem constants
#define B2     2
#define CIN    31
#define CC     64      // conv out channels / GAT dim
#define NN     4096    // 64*64 nodes
#define NCH    8       // kNN j-splits (512 j each)

typedef short bf16x8 __attribute__((ext_vector_type(8)));
typedef float f32x4  __attribute__((ext_vector_type(4)));

__device__ inline unsigned short f2bf(float f) {
  union { float f; unsigned u; } v; v.f = f;
  unsigned r = (v.u + 0x7fffu + ((v.u >> 16) & 1u)) >> 16;
  return (unsigned short)r;
}
__device__ inline float bf2f(unsigned short h) {
  union { float f; unsigned u; } v; v.u = ((unsigned)h) << 16;
  return v.f;
}

// ---------------- workspace layout (in 4-byte elements) ----------------
constexpr int OF_YN   = 0;                         // [B,N,64] fp32
constexpr int OF_SQ   = OF_YN   + B2*NN*CC;        // [B,N]
constexpr int OF_HCAT = OF_SQ   + B2*NN;           // [B,N,128]
constexpr int OF_FV   = OF_HCAT + B2*NN*128;       // 4 x [B*N]
constexpr int OF_HAGG = OF_FV   + 4*B2*NN;         // [B,N,128]
constexpr int OF_HO   = OF_HAGG + B2*NN*128;       // [B,N,64]
constexpr int OF_FO   = OF_HO   + B2*NN*CC;        // 2 x [B*N]
constexpr int OF_Z    = OF_FO   + 2*B2*NN;         // [B,N,64]
constexpr int OF_PD   = OF_Z    + B2*NN*CC;        // partial top7 dists [B*N][NCH][7]
constexpr int OF_PI   = OF_PD   + B2*NN*NCH*7;     // partial top7 idx (int)
constexpr int OF_NBR  = OF_PI   + B2*NN*NCH*7;     // [B*N][7] neighbor idx (int)
constexpr int OF_WT   = OF_NBR  + B2*NN*7;         // convT weights [9][64][64]
constexpr int OF_WHT  = OF_WT   + 9*64*64;         // head conv weights [279][64]
constexpr int OF_YNH  = OF_WHT  + 279*64;          // bf16 hi [B,N,64] (ushort)
constexpr int OF_YNL  = OF_YNH  + B2*NN*CC/2;      // bf16 lo [B,N,64] (ushort)

// ---------------- K0: weight transposes ----------------
__global__ __launch_bounds__(256) void k_prep(const float* __restrict__ wlast,
                                              const float* __restrict__ whead,
                                              float* __restrict__ wT,
                                              float* __restrict__ whT) {
  int idx = blockIdx.x*256 + threadIdx.x;
  if (idx < 36864) {
    int co = idx & 63, ci = (idx >> 6) & 63, kk = idx >> 12;
    wT[idx] = wlast[(ci*64 + co)*9 + kk];
  } else if (idx < 36864 + 279*64) {
    int j = idx - 36864;
    int c = j & 63, q = j >> 6;
    whT[j] = whead[c*279 + q];
  }
}

// ---------------- K1: head conv + sq + bf16 split (1024 blocks, 4/CU) -------
__global__ __launch_bounds__(256) void k_head(const float* __restrict__ x,
                                              const float* __restrict__ whT,
                                              const float* __restrict__ bias,
                                              float* __restrict__ yn,
                                              float* __restrict__ sq,
                                              unsigned short* __restrict__ ynh,
                                              unsigned short* __restrict__ ynl) {
  int lane = threadIdx.x & 63, wv = threadIdx.x >> 6;
  int gbase = blockIdx.x*8 + wv*2;               // 2 nodes per wave
  __shared__ __align__(16) float patch[4][2][280];
  for (int nn = 0; nn < 2; ++nn) {
    int g = gbase + nn;
    int b = g >> 12, n = g & 4095;
    int oh = n >> 6, ow = n & 63;
    for (int q = lane; q < 279; q += 64) {
      int ci = q / 9, r = q - ci*9;
      int ky = r / 3, kx = r - ky*3;
      int ih = 2*oh - 1 + ky, iw = 2*ow - 1 + kx;
      float v = 0.f;
      if (ih >= 0 && ih < 128 && iw >= 0 && iw < 128)
        v = x[((b*CIN + ci)*128 + ih)*128 + iw];
      patch[wv][nn][q] = v;
    }
  }
  __syncthreads();
  int c = lane;
  float acc[2];
  float bv = bias[c];
  acc[0] = bv; acc[1] = bv;
  for (int q = 0; q < 276; q += 4) {
    float w0 = whT[q*64 + c];
    float w1 = whT[(q+1)*64 + c];
    float w2 = whT[(q+2)*64 + c];
    float w3 = whT[(q+3)*64 + c];
    #pragma unroll
    for (int nn = 0; nn < 2; ++nn) {
      float4 pv = *(const float4*)&patch[wv][nn][q];
      acc[nn] = fmaf(pv.x, w0, acc[nn]);
      acc[nn] = fmaf(pv.y, w1, acc[nn]);
      acc[nn] = fmaf(pv.z, w2, acc[nn]);
      acc[nn] = fmaf(pv.w, w3, acc[nn]);
    }
  }
  for (int q = 276; q < 279; ++q) {
    float wq = whT[q*64 + c];
    #pragma unroll
    for (int nn = 0; nn < 2; ++nn) acc[nn] = fmaf(patch[wv][nn][q], wq, acc[nn]);
  }
  for (int nn = 0; nn < 2; ++nn) {
    int g = gbase + nn;
    float y = acc[nn];
    yn[g*64 + c] = y;
    unsigned short hb = f2bf(y);
    ynh[g*64 + c] = hb;
    ynl[g*64 + c] = f2bf(y - bf2f(hb));
    float s = y*y;
    #pragma unroll
    for (int off = 32; off > 0; off >>= 1) s += __shfl_xor(s, off);
    if (lane == 0) sq[g] = s;
  }
}

// ---------------- K2: MFMA Gram + branchless packed-key top-7 ---------------
// Keys: clamp(d2,0) -> (bits & ~127) | lane-local element index (7 bits).
// Positive-float bits are uint-monotonic; low-bit index gives smaller-j
// tie-break for free. Top-7 = 7-deep min/max sorted insert (14 VALU/elem,
// no branches, no indexed register writes).
__global__ __launch_bounds__(256, 4) void k_knn6(const unsigned short* __restrict__ ynh,
                                                 const unsigned short* __restrict__ ynl,
                                                 const float* __restrict__ sq,
                                                 float* __restrict__ pd,
                                                 int* __restrict__ pidx) {
  __shared__ __align__(16) unsigned short Bh[2][64*72];
  __shared__ __align__(16) unsigned short Bl[2][64*72];
  __shared__ __align__(16) float sqjs[2][64];

  int b = blockIdx.z, ib = blockIdx.x, jsp = blockIdx.y;
  int i0 = ib*64, jbase = jsp*512;
  int tid = threadIdx.x;
  int lane = tid & 63, w = tid >> 6;
  int quad = lane >> 4, m = lane & 15;

  const unsigned short* ynh_b = ynh + (size_t)b*NN*64;
  const unsigned short* ynl_b = ynl + (size_t)b*NN*64;
  const float* sq_b = sq + b*NN;

  int irow = i0 + w*16 + m;
  bf16x8 bhf0 = *(const bf16x8*)(ynh_b + irow*64 + quad*8);
  bf16x8 bhf1 = *(const bf16x8*)(ynh_b + irow*64 + 32 + quad*8);
  bf16x8 blf0 = *(const bf16x8*)(ynl_b + irow*64 + quad*8);
  bf16x8 blf1 = *(const bf16x8*)(ynl_b + irow*64 + 32 + quad*8);
  float sqi = sq_b[irow];

  unsigned k7[7];
  #pragma unroll
  for (int k = 0; k < 7; ++k) k7[k] = 0xFFFFFFFFu;

  int srow = tid >> 3, oct = tid & 7;

  {
    int jt = jbase;
    *(uint4*)&Bh[0][srow*72 + oct*8]      = *(const uint4*)(ynh_b + (jt + srow)*64 + oct*8);
    *(uint4*)&Bh[0][(srow+32)*72 + oct*8] = *(const uint4*)(ynh_b + (jt + srow + 32)*64 + oct*8);
    *(uint4*)&Bl[0][srow*72 + oct*8]      = *(const uint4*)(ynl_b + (jt + srow)*64 + oct*8);
    *(uint4*)&Bl[0][(srow+32)*72 + oct*8] = *(const uint4*)(ynl_b + (jt + srow + 32)*64 + oct*8);
    if (tid < 64) sqjs[0][tid] = sq_b[jt + tid];
  }
  __syncthreads();

  #pragma unroll 1
  for (int c = 0; c < 8; ++c) {
    int buf = c & 1, nbuf = buf ^ 1;
    uint4 gh0, gh1, gl0, gl1; float gsq = 0.f;
    if (c < 7) {
      int jt = jbase + (c+1)*64;
      gh0 = *(const uint4*)(ynh_b + (jt + srow)*64 + oct*8);
      gh1 = *(const uint4*)(ynh_b + (jt + srow + 32)*64 + oct*8);
      gl0 = *(const uint4*)(ynl_b + (jt + srow)*64 + oct*8);
      gl1 = *(const uint4*)(ynl_b + (jt + srow + 32)*64 + oct*8);
      if (tid < 64) gsq = sq_b[jt + tid];
    }
    unsigned lc = (unsigned)(c << 4);      // chunk base of lane-local index
    #pragma unroll
    for (int jn = 0; jn < 4; ++jn) {
      const int ro = (jn*16 + m)*72 + quad*8;
      bf16x8 ajh0 = *(const bf16x8*)&Bh[buf][ro];
      bf16x8 ajh1 = *(const bf16x8*)&Bh[buf][ro + 32];
      bf16x8 ajl0 = *(const bf16x8*)&Bl[buf][ro];
      bf16x8 ajl1 = *(const bf16x8*)&Bl[buf][ro + 32];
      f32x4 sq4 = *(const f32x4*)&sqjs[buf][jn*16 + quad*4];

      f32x4 a = (f32x4){0.f, 0.f, 0.f, 0.f};
      a = __builtin_amdgcn_mfma_f32_16x16x32_bf16(ajh0, bhf0, a, 0, 0, 0);
      a = __builtin_amdgcn_mfma_f32_16x16x32_bf16(ajl0, bhf0, a, 0, 0, 0);
      a = __builtin_amdgcn_mfma_f32_16x16x32_bf16(ajh0, blf0, a, 0, 0, 0);
      a = __builtin_amdgcn_mfma_f32_16x16x32_bf16(ajh1, bhf1, a, 0, 0, 0);
      a = __builtin_amdgcn_mfma_f32_16x16x32_bf16(ajl1, bhf1, a, 0, 0, 0);
      a = __builtin_amdgcn_mfma_f32_16x16x32_bf16(ajh1, blf1, a, 0, 0, 0);

      #pragma unroll
      for (int r = 0; r < 4; ++r) {
        float d2v = fmaf(-2.f, a[r], sqi + sq4[r]);
        d2v = fmaxf(d2v, 0.f);             // == reference clip(d2, 0)
        unsigned mx = (__float_as_uint(d2v) & 0xFFFFFF80u) | (lc + (unsigned)(jn*4 + r));
        #pragma unroll
        for (int t7 = 0; t7 < 7; ++t7) {
          unsigned old = k7[t7];
          k7[t7] = (mx < old) ? mx : old;
          mx     = (mx < old) ? old : mx;
        }
      }
    }
    if (c < 7) {
      *(uint4*)&Bh[nbuf][srow*72 + oct*8]      = gh0;
      *(uint4*)&Bh[nbuf][(srow+32)*72 + oct*8] = gh1;
      *(uint4*)&Bl[nbuf][srow*72 + oct*8]      = gl0;
      *(uint4*)&Bl[nbuf][(srow+32)*72 + oct*8] = gl1;
      if (tid < 64) sqjs[nbuf][tid] = gsq;
    }
    __syncthreads();
  }

  // unpack keys -> (truncated d2, global j); merge the row's 4 quads
  float* cd = (float*)&Bh[0][0];   // [64][28]
  int*   ci = (int*)&Bh[1][0];
  int row = w*16 + m;
  #pragma unroll
  for (int k = 0; k < 7; ++k) {
    unsigned key = k7[k];
    int local = key & 127;
    int cch = local >> 4, jn2 = (local >> 2) & 3, r2 = local & 3;
    cd[row*28 + quad*7 + k] = __uint_as_float(key & 0xFFFFFF80u);
    ci[row*28 + quad*7 + k] = jbase + cch*64 + jn2*16 + quad*4 + r2;
  }
  __syncthreads();
  if (tid < 64) {
    float md[7]; int mi[7];
    #pragma unroll
    for (int k = 0; k < 7; ++k) { md[k] = 3.0e38f; mi[k] = 0x7fffffff; }
    for (int e = 0; e < 28; ++e) {
      float d = cd[tid*28 + e]; int jj = ci[tid*28 + e];
      if (d < md[6] || (d == md[6] && jj < mi[6])) {
        int k = 6;
        #pragma unroll
        for (int t = 5; t >= 0; --t)
          if (d < md[t] || (d == md[t] && jj < mi[t])) { md[t+1] = md[t]; mi[t+1] = mi[t]; k = t; }
        md[k] = d; mi[k] = jj;
      }
    }
    int g = b*NN + i0 + tid;
    int base = (g*NCH + jsp)*7;
    #pragma unroll
    for (int k = 0; k < 7; ++k) { pd[base+k] = md[k]; pidx[base+k] = mi[k]; }
  }
}

// ---------------- K4: fused [hcat GEMM + f-vectors] and [top7 merge] --------
__global__ __launch_bounds__(256) void k_hm(const float* __restrict__ yn,
                                            const float* __restrict__ W0,
                                            const float* __restrict__ W1,
                                            const float* __restrict__ a0,
                                            const float* __restrict__ a1,
                                            float* __restrict__ hcat,
                                            float* __restrict__ fv,
                                            const float* __restrict__ pd,
                                            const int* __restrict__ pidx,
                                            int* __restrict__ nbr) {
  __shared__ __align__(16) float yt[16*64];
  int tid = threadIdx.x;
  if (blockIdx.x >= 512) {
    // ---- merge path ----
    int g = (blockIdx.x - 512)*256 + tid;    // 0..8191
    float d7[7]; int x7[7];
    #pragma unroll
    for (int k = 0; k < 7; ++k) { d7[k] = 3.0e38f; x7[k] = 0x7fffffff; }
    int base = g*NCH*7;
    for (int e = 0; e < NCH*7; ++e) {
      float d = pd[base+e]; int jj = pidx[base+e];
      if (d < d7[6]) {
        int k = 6;
        #pragma unroll
        for (int t = 5; t >= 0; --t) {
          if (d < d7[t]) { d7[t+1] = d7[t]; x7[t+1] = x7[t]; k = t; }
        }
        d7[k] = d; x7[k] = jj;
      }
    }
    #pragma unroll
    for (int k = 0; k < 7; ++k) nbr[g*7 + k] = x7[k];
    return;
  }
  // ---- hcat path ----
  int b = blockIdx.x >> 8, n0 = (blockIdx.x & 255)*16;
  int c = tid & 127, ng = tid >> 7, lane = tid & 63;
  float wreg[64];
  {
    const float* Wp = (c < 64) ? (W0 + c) : (W1 + (c - 64));
    #pragma unroll
    for (int k = 0; k < 64; ++k) wreg[k] = Wp[k*64];
  }
  ((float4*)yt)[tid] = ((const float4*)(yn + (b*NN + n0)*64))[tid];
  __syncthreads();
  int head = c >> 6;
  float av1 = head ? a1[lane] : a0[lane];
  float av2 = head ? a1[64 + lane] : a0[64 + lane];
  for (int nn = 0; nn < 8; ++nn) {
    int node = ng*8 + nn;
    const float* yr = yt + node*64;
    float acc = 0.f;
    #pragma unroll
    for (int k4 = 0; k4 < 16; ++k4) {
      float4 yv = *(const float4*)(yr + k4*4);
      acc = fmaf(yv.x, wreg[k4*4+0], acc);
      acc = fmaf(yv.y, wreg[k4*4+1], acc);
      acc = fmaf(yv.z, wreg[k4*4+2], acc);
      acc = fmaf(yv.w, wreg[k4*4+3], acc);
    }
    hcat[(b*NN + n0 + node)*128 + c] = acc;
    float s1 = acc*av1, s2 = acc*av2;
    #pragma unroll
    for (int off = 32; off > 0; off >>= 1) {
      s1 += __shfl_xor(s1, off); s2 += __shfl_xor(s2, off);
    }
    if (lane == 0) {
      int gg = (b << 12) + n0 + node;
      fv[head*16384 + gg] = s1;
      fv[head*16384 + 8192 + gg] = s2;
    }
  }
}

// ---------------- K6: GAT layer1 aggregation (2 heads) + relu ---------------
__global__ __launch_bounds__(256) void k_agg1(const float* __restrict__ hcat,
                                              const float* __restrict__ fv,
                                              const int* __restrict__ nbr,
                                              float* __restrict__ hagg) {
  int g = blockIdx.x*2 + (threadIdx.x >> 7);
  int c = threadIdx.x & 127;
  int b = g >> 12;
  int head = c >> 6;
  int jj[7];
  #pragma unroll
  for (int t = 0; t < 7; ++t) jj[t] = nbr[g*7 + t];
  float f1 = fv[head*16384 + g];
  const float* f2p = fv + head*16384 + 8192 + (b << 12);
  float e[7], mx = -3.0e38f;
  #pragma unroll
  for (int t = 0; t < 7; ++t) {
    float v = f1 + f2p[jj[t]];
    v = (v >= 0.f) ? v : 0.2f*v;
    e[t] = v; mx = fmaxf(mx, v);
  }
  float wgt[7], s = 0.f;
  #pragma unroll
  for (int t = 0; t < 7; ++t) { wgt[t] = expf(e[t] - mx); s += wgt[t]; }
  float acc = 0.f;
  #pragma unroll
  for (int t = 0; t < 7; ++t)
    acc += (wgt[t]/s) * hcat[((b << 12) + jj[t])*128 + c];
  hagg[g*128 + c] = fmaxf(acc, 0.f);
}

// ---------------- K7: ho = hagg @ W_out + fused f-vectors (reg-W halves) ----
__global__ __launch_bounds__(256) void k_ho(const float* __restrict__ hagg,
                                            const float* __restrict__ Wout,
                                            const float* __restrict__ aout,
                                            float* __restrict__ ho,
                                            float* __restrict__ fo) {
  __shared__ __align__(16) float ht[16*128];
  __shared__ float part[16][64];
  int b = blockIdx.x >> 8, n0 = (blockIdx.x & 255)*16;
  int tid = threadIdx.x;
  int c = tid & 63, g = (tid >> 6) & 1, ng = tid >> 7;
  float wreg[64];
  #pragma unroll
  for (int k = 0; k < 64; ++k) wreg[k] = Wout[(g*64 + k)*64 + c];
  {
    const float4* src = (const float4*)(hagg + (b*NN + n0)*128);
    ((float4*)ht)[tid] = src[tid];
    ((float4*)ht)[tid + 256] = src[tid + 256];
  }
  __syncthreads();
  float accs[8];
  for (int nn = 0; nn < 8; ++nn) {
    int node = ng*8 + nn;
    const float* hr = ht + node*128 + g*64;
    float acc = 0.f;
    #pragma unroll
    for (int k4 = 0; k4 < 16; ++k4) {
      float4 hv = *(const float4*)(hr + k4*4);
      acc = fmaf(hv.x, wreg[k4*4+0], acc);
      acc = fmaf(hv.y, wreg[k4*4+1], acc);
      acc = fmaf(hv.z, wreg[k4*4+2], acc);
      acc = fmaf(hv.w, wreg[k4*4+3], acc);
    }
    accs[nn] = acc;
  }
  if (g == 0) {
    #pragma unroll
    for (int nn = 0; nn < 8; ++nn) part[ng*8 + nn][c] = accs[nn];
  }
  __syncthreads();
  if (g == 1) {
    float av1 = aout[c], av2 = aout[64 + c];
    for (int nn = 0; nn < 8; ++nn) {
      int node = ng*8 + nn;
      float acc = accs[nn] + part[node][c];
      ho[(b*NN + n0 + node)*64 + c] = acc;
      float s1 = acc*av1, s2 = acc*av2;
      #pragma unroll
      for (int off = 32; off > 0; off >>= 1) {
        s1 += __shfl_xor(s1, off); s2 += __shfl_xor(s2, off);
      }
      if (c == 0) {
        int gg = (b << 12) + n0 + node;
        fo[gg] = s1;
        fo[8192 + gg] = s2;
      }
    }
  }
}

// ---------------- K9: layer2 agg + elu + log_softmax ------------------------
__global__ __launch_bounds__(256) void k_agg2(const float* __restrict__ ho,
                                              const float* __restrict__ fo,
                                              const int* __restrict__ nbr,
                                              float* __restrict__ zbuf) {
  int g = blockIdx.x*4 + (threadIdx.x >> 6);
  int c = threadIdx.x & 63;
  int b = g >> 12;
  int jj[7];
  #pragma unroll
  for (int t = 0; t < 7; ++t) jj[t] = nbr[g*7 + t];
  float f1 = fo[g];
  const float* f2p = fo + 8192 + (b << 12);
  float e[7], mx = -3.0e38f;
  #pragma unroll
  for (int t = 0; t < 7; ++t) {
    float v = f1 + f2p[jj[t]];
    v = (v >= 0.f) ? v : 0.2f*v;
    e[t] = v; mx = fmaxf(mx, v);
  }
  float wgt[7], s = 0.f;
  #pragma unroll
  for (int t = 0; t < 7; ++t) { wgt[t] = expf(e[t] - mx); s += wgt[t]; }
  float acc = 0.f;
  #pragma unroll
  for (int t = 0; t < 7; ++t)
    acc += (wgt[t]/s) * ho[((b << 12) + jj[t])*64 + c];
  float v = (acc > 0.f) ? acc : expm1f(acc);
  float mm = v;
  #pragma unroll
  for (int off = 32; off > 0; off >>= 1) mm = fmaxf(mm, __shfl_xor(mm, off));
  float ex = expf(v - mm), ss = ex;
  #pragma unroll
  for (int off = 32; off > 0; off >>= 1) ss += __shfl_xor(ss, off);
  zbuf[g*64 + c] = v - mm - logf(ss);
}

// ---------------- K10: ConvTranspose2d v3 — half-row blocks (512, 2/CU) -----
__global__ __launch_bounds__(256) void k_convt3(const float* __restrict__ z,
                                                const float* __restrict__ wT,
                                                const float* __restrict__ bias,
                                                float* __restrict__ out) {
  __shared__ __align__(16) float lds[8704];    // 34816 B
  float* zt = lds;              // [2 rows][64 ci][36]
  float* ws = lds + 4608;       // [64 ci][64 co]
  float* so = lds;              // [64 co][65] epilogue alias

  int oy = blockIdx.x, xh = blockIdx.y, b = blockIdx.z;
  int r = oy >> 1, pi = oy & 1;
  int tid = threadIdx.x;
  int colo = tid & 15, pgrp = tid >> 4;
  int co4 = colo*4, m0 = pgrp*2;
  int ix0 = xh*32;

  int nrows = pi ? 2 : 1;
  for (int row = 0; row < nrows; ++row) {
    int iy = r + row;
    const float* zsrc = z + (((b << 12) + iy*64) << 6);
    for (int idx = tid; idx < 2112; idx += 256) {
      int ix = idx >> 6, ci = idx & 63;
      int ixg = ix0 + ix;
      float v = 0.f;
      if (ixg < 64 && iy < 64) v = zsrc[ixg*64 + ci];
      zt[row*2304 + ci*36 + ix] = v;
    }
  }

  float acc[2][2][4];
  {
    float4 bv = *(const float4*)&bias[co4];
    #pragma unroll
    for (int chi = 0; chi < 2; ++chi)
      #pragma unroll
      for (int k = 0; k < 2; ++k) {
        acc[chi][k][0] = bv.x; acc[chi][k][1] = bv.y;
        acc[chi][k][2] = bv.z; acc[chi][k][3] = bv.w;
      }
  }

  int kys[2], rows[2], nky;
  if (pi == 0) { kys[0] = 1; rows[0] = 0; nky = 1; }
  else         { kys[0] = 2; rows[0] = 0; kys[1] = 0; rows[1] = 1; nky = 2; }

  for (int t = 0; t < nky; ++t) {
    const float* zrow = zt + rows[t]*2304;
    #pragma unroll
    for (int kx = 0; kx < 3; ++kx) {
      const float* wsrc = wT + (kys[t]*3 + kx)*4096;
      __syncthreads();
      for (int idx = tid; idx < 4096; idx += 256) ws[idx] = wsrc[idx];
      __syncthreads();
      const int chi = (kx == 1) ? 0 : 1;
      const int xoff = (kx == 0) ? 1 : 0;
      float* ap = &acc[chi][0][0];
      for (int ci = 0; ci < 64; ++ci) {
        float4 wv = *(const float4*)&ws[ci*64 + co4];
        const float* zp = zrow + ci*36 + m0;
        float z0, z1;
        if (xoff == 0) { float2 za = *(const float2*)zp; z0 = za.x; z1 = za.y; }
        else           { float2 za = *(const float2*)zp; z0 = za.y; z1 = zp[2]; }
        ap[0] = fmaf(z0, wv.x, ap[0]);
        ap[1] = fmaf(z0, wv.y, ap[1]);
        ap[2] = fmaf(z0, wv.z, ap[2]);
        ap[3] = fmaf(z0, wv.w, ap[3]);
        ap[4] = fmaf(z1, wv.x, ap[4]);
        ap[5] = fmaf(z1, wv.y, ap[5]);
        ap[6] = fmaf(z1, wv.z, ap[6]);
        ap[7] = fmaf(z1, wv.w, ap[7]);
      }
    }
  }

  __syncthreads();
  #pragma unroll
  for (int chi = 0; chi < 2; ++chi)
    #pragma unroll
    for (int k = 0; k < 2; ++k)
      #pragma unroll
      for (int cc = 0; cc < 4; ++cc)
        so[(co4 + cc)*65 + 2*(m0 + k) + chi] = acc[chi][k][cc];
  __syncthreads();
  for (int idx = tid; idx < 4096; idx += 256) {
    int co = idx >> 6, ox = idx & 63;
    out[(((b << 6) + co)*128 + oy)*128 + xh*64 + ox] = so[co*65 + ox];
  }
}

// ---------------- launch ----------------------------------------------------
extern "C" void kernel_launch(void* const* d_in, const int* in_sizes, int n_in,
                              void* d_out, int out_size, void* d_ws, size_t ws_size,
                              hipStream_t stream) {
  const float* x      = (const float*)d_in[0];
  const float* w_head = (const float*)d_in[1];
  const float* b_head = (const float*)d_in[2];
  const float* W0     = (const float*)d_in[3];
  const float* a0     = (const float*)d_in[4];
  const float* W1     = (const float*)d_in[5];
  const float* a1     = (const float*)d_in[6];
  const float* W_out  = (const float*)d_in[7];
  const float* a_out  = (const float*)d_in[8];
  const float* w_last = (const float*)d_in[9];
  const float* b_last = (const float*)d_in[10];
  float* out = (float*)d_out;

  float* wsf = (float*)d_ws;
  int*   wsi = (int*)d_ws;
  float* yn   = wsf + OF_YN;
  float* sq   = wsf + OF_SQ;
  float* hcat = wsf + OF_HCAT;
  float* fv   = wsf + OF_FV;
  float* hagg = wsf + OF_HAGG;
  float* ho   = wsf + OF_HO;
  float* fo   = wsf + OF_FO;
  float* zbuf = wsf + OF_Z;
  float* pd   = wsf + OF_PD;
  int*   pidx = wsi + OF_PI;
  int*   nbr  = wsi + OF_NBR;
  float* wT   = wsf + OF_WT;
  float* whT  = wsf + OF_WHT;
  unsigned short* ynh = (unsigned short*)(wsf + OF_YNH);
  unsigned short* ynl = (unsigned short*)(wsf + OF_YNL);

  hipLaunchKernelGGL(k_prep,  dim3(214), dim3(256), 0, stream, w_last, w_head, wT, whT);
  hipLaunchKernelGGL(k_head,  dim3(1024), dim3(256), 0, stream, x, whT, b_head, yn, sq, ynh, ynl);
  hipLaunchKernelGGL(k_knn6,  dim3(64, NCH, 2), dim3(256), 0, stream, ynh, ynl, sq, pd, pidx);
  hipLaunchKernelGGL(k_hm,    dim3(544), dim3(256), 0, stream, yn, W0, W1, a0, a1, hcat, fv, pd, pidx, nbr);
  hipLaunchKernelGGL(k_agg1,  dim3(4096), dim3(256), 0, stream, hcat, fv, nbr, hagg);
  hipLaunchKernelGGL(k_ho,    dim3(512), dim3(256), 0, stream, hagg, W_out, a_out, ho, fo);
  hipLaunchKernelGGL(k_agg2,  dim3(2048), dim3(256), 0, stream, ho, fo, nbr, zbuf);
  hipLaunchKernelGGL(k_convt3, dim3(128, 2, 2), dim3(256), 0, stream, zbuf, wT, b_last, out);
}

// Round 9
// 196.037 us; speedup vs baseline: 1.4431x; 1.1737x over previous
//
#include <hip/hip_runtime.h>
#include <math.h>

// Problem constants
#define B2     2
#define CIN    31
#define CC     64      // conv out channels / GAT dim
#define NN     4096    // 64*64 nodes
#define NCH    8       // kNN j-splits (512 j each)

typedef short bf16x8 __attribute__((ext_vector_type(8)));
typedef float f32x4  __attribute__((ext_vector_type(4)));

__device__ inline unsigned short f2bf(float f) {
  union { float f; unsigned u; } v; v.f = f;
  unsigned r = (v.u + 0x7fffu + ((v.u >> 16) & 1u)) >> 16;
  return (unsigned short)r;
}
__device__ inline float bf2f(unsigned short h) {
  union { float f; unsigned u; } v; v.u = ((unsigned)h) << 16;
  return v.f;
}

// ---------------- workspace layout (in 4-byte elements) ----------------
constexpr int OF_YN   = 0;                         // [B,N,64] fp32
constexpr int OF_SQ   = OF_YN   + B2*NN*CC;        // [B,N]
constexpr int OF_HCAT = OF_SQ   + B2*NN;           // [B,N,128]
constexpr int OF_FV   = OF_HCAT + B2*NN*128;       // 4 x [B*N]
constexpr int OF_HAGG = OF_FV   + 4*B2*NN;         // [B,N,128]
constexpr int OF_HO   = OF_HAGG + B2*NN*128;       // [B,N,64]
constexpr int OF_FO   = OF_HO   + B2*NN*CC;        // 2 x [B*N]
constexpr int OF_Z    = OF_FO   + 2*B2*NN;         // [B,N,64]
constexpr int OF_PD   = OF_Z    + B2*NN*CC;        // partial top7 dists [B*N][NCH][7]
constexpr int OF_PI   = OF_PD   + B2*NN*NCH*7;     // partial top7 idx (int)
constexpr int OF_NBR  = OF_PI   + B2*NN*NCH*7;     // [B*N][7] neighbor idx (int)
constexpr int OF_WT   = OF_NBR  + B2*NN*7;         // convT weights [9][64][64]
constexpr int OF_WHT  = OF_WT   + 9*64*64;         // head conv weights [279][64]
constexpr int OF_YNH  = OF_WHT  + 279*64;          // bf16 hi [B,N,64] (ushort)
constexpr int OF_YNL  = OF_YNH  + B2*NN*CC/2;      // bf16 lo [B,N,64] (ushort)

// ---------------- K0: weight transposes ----------------
__global__ __launch_bounds__(256) void k_prep(const float* __restrict__ wlast,
                                              const float* __restrict__ whead,
                                              float* __restrict__ wT,
                                              float* __restrict__ whT) {
  int idx = blockIdx.x*256 + threadIdx.x;
  if (idx < 36864) {
    int co = idx & 63, ci = (idx >> 6) & 63, kk = idx >> 12;
    wT[idx] = wlast[(ci*64 + co)*9 + kk];
  } else if (idx < 36864 + 279*64) {
    int j = idx - 36864;
    int c = j & 63, q = j >> 6;
    whT[j] = whead[c*279 + q];
  }
}

// ---------------- K1: head conv + sq + bf16 split (1024 blocks, 4/CU) -------
__global__ __launch_bounds__(256) void k_head(const float* __restrict__ x,
                                              const float* __restrict__ whT,
                                              const float* __restrict__ bias,
                                              float* __restrict__ yn,
                                              float* __restrict__ sq,
                                              unsigned short* __restrict__ ynh,
                                              unsigned short* __restrict__ ynl) {
  int lane = threadIdx.x & 63, wv = threadIdx.x >> 6;
  int gbase = blockIdx.x*8 + wv*2;               // 2 nodes per wave
  __shared__ __align__(16) float patch[4][2][280];
  for (int nn = 0; nn < 2; ++nn) {
    int g = gbase + nn;
    int b = g >> 12, n = g & 4095;
    int oh = n >> 6, ow = n & 63;
    for (int q = lane; q < 279; q += 64) {
      int ci = q / 9, r = q - ci*9;
      int ky = r / 3, kx = r - ky*3;
      int ih = 2*oh - 1 + ky, iw = 2*ow - 1 + kx;
      float v = 0.f;
      if (ih >= 0 && ih < 128 && iw >= 0 && iw < 128)
        v = x[((b*CIN + ci)*128 + ih)*128 + iw];
      patch[wv][nn][q] = v;
    }
  }
  __syncthreads();
  int c = lane;
  float acc[2];
  float bv = bias[c];
  acc[0] = bv; acc[1] = bv;
  for (int q = 0; q < 276; q += 4) {
    float w0 = whT[q*64 + c];
    float w1 = whT[(q+1)*64 + c];
    float w2 = whT[(q+2)*64 + c];
    float w3 = whT[(q+3)*64 + c];
    #pragma unroll
    for (int nn = 0; nn < 2; ++nn) {
      float4 pv = *(const float4*)&patch[wv][nn][q];
      acc[nn] = fmaf(pv.x, w0, acc[nn]);
      acc[nn] = fmaf(pv.y, w1, acc[nn]);
      acc[nn] = fmaf(pv.z, w2, acc[nn]);
      acc[nn] = fmaf(pv.w, w3, acc[nn]);
    }
  }
  for (int q = 276; q < 279; ++q) {
    float wq = whT[q*64 + c];
    #pragma unroll
    for (int nn = 0; nn < 2; ++nn) acc[nn] = fmaf(patch[wv][nn][q], wq, acc[nn]);
  }
  for (int nn = 0; nn < 2; ++nn) {
    int g = gbase + nn;
    float y = acc[nn];
    yn[g*64 + c] = y;
    unsigned short hb = f2bf(y);
    ynh[g*64 + c] = hb;
    ynl[g*64 + c] = f2bf(y - bf2f(hb));
    float s = y*y;
    #pragma unroll
    for (int off = 32; off > 0; off >>= 1) s += __shfl_xor(s, off);
    if (lane == 0) sq[g] = s;
  }
}

// ---------------- K2: MFMA Gram + branchless packed-key top-7 ---------------
__global__ __launch_bounds__(256, 4) void k_knn6(const unsigned short* __restrict__ ynh,
                                                 const unsigned short* __restrict__ ynl,
                                                 const float* __restrict__ sq,
                                                 float* __restrict__ pd,
                                                 int* __restrict__ pidx) {
  __shared__ __align__(16) unsigned short Bh[2][64*72];
  __shared__ __align__(16) unsigned short Bl[2][64*72];
  __shared__ __align__(16) float sqjs[2][64];

  int b = blockIdx.z, ib = blockIdx.x, jsp = blockIdx.y;
  int i0 = ib*64, jbase = jsp*512;
  int tid = threadIdx.x;
  int lane = tid & 63, w = tid >> 6;
  int quad = lane >> 4, m = lane & 15;

  const unsigned short* ynh_b = ynh + (size_t)b*NN*64;
  const unsigned short* ynl_b = ynl + (size_t)b*NN*64;
  const float* sq_b = sq + b*NN;

  int irow = i0 + w*16 + m;
  bf16x8 bhf0 = *(const bf16x8*)(ynh_b + irow*64 + quad*8);
  bf16x8 bhf1 = *(const bf16x8*)(ynh_b + irow*64 + 32 + quad*8);
  bf16x8 blf0 = *(const bf16x8*)(ynl_b + irow*64 + quad*8);
  bf16x8 blf1 = *(const bf16x8*)(ynl_b + irow*64 + 32 + quad*8);
  float sqi = sq_b[irow];

  unsigned k7[7];
  #pragma unroll
  for (int k = 0; k < 7; ++k) k7[k] = 0xFFFFFFFFu;

  int srow = tid >> 3, oct = tid & 7;

  {
    int jt = jbase;
    *(uint4*)&Bh[0][srow*72 + oct*8]      = *(const uint4*)(ynh_b + (jt + srow)*64 + oct*8);
    *(uint4*)&Bh[0][(srow+32)*72 + oct*8] = *(const uint4*)(ynh_b + (jt + srow + 32)*64 + oct*8);
    *(uint4*)&Bl[0][srow*72 + oct*8]      = *(const uint4*)(ynl_b + (jt + srow)*64 + oct*8);
    *(uint4*)&Bl[0][(srow+32)*72 + oct*8] = *(const uint4*)(ynl_b + (jt + srow + 32)*64 + oct*8);
    if (tid < 64) sqjs[0][tid] = sq_b[jt + tid];
  }
  __syncthreads();

  #pragma unroll 1
  for (int c = 0; c < 8; ++c) {
    int buf = c & 1, nbuf = buf ^ 1;
    uint4 gh0, gh1, gl0, gl1; float gsq = 0.f;
    if (c < 7) {
      int jt = jbase + (c+1)*64;
      gh0 = *(const uint4*)(ynh_b + (jt + srow)*64 + oct*8);
      gh1 = *(const uint4*)(ynh_b + (jt + srow + 32)*64 + oct*8);
      gl0 = *(const uint4*)(ynl_b + (jt + srow)*64 + oct*8);
      gl1 = *(const uint4*)(ynl_b + (jt + srow + 32)*64 + oct*8);
      if (tid < 64) gsq = sq_b[jt + tid];
    }
    unsigned lc = (unsigned)(c << 4);      // chunk base of lane-local index
    #pragma unroll
    for (int jn = 0; jn < 4; ++jn) {
      const int ro = (jn*16 + m)*72 + quad*8;
      bf16x8 ajh0 = *(const bf16x8*)&Bh[buf][ro];
      bf16x8 ajh1 = *(const bf16x8*)&Bh[buf][ro + 32];
      bf16x8 ajl0 = *(const bf16x8*)&Bl[buf][ro];
      bf16x8 ajl1 = *(const bf16x8*)&Bl[buf][ro + 32];
      f32x4 sq4 = *(const f32x4*)&sqjs[buf][jn*16 + quad*4];

      f32x4 a = (f32x4){0.f, 0.f, 0.f, 0.f};
      a = __builtin_amdgcn_mfma_f32_16x16x32_bf16(ajh0, bhf0, a, 0, 0, 0);
      a = __builtin_amdgcn_mfma_f32_16x16x32_bf16(ajl0, bhf0, a, 0, 0, 0);
      a = __builtin_amdgcn_mfma_f32_16x16x32_bf16(ajh0, blf0, a, 0, 0, 0);
      a = __builtin_amdgcn_mfma_f32_16x16x32_bf16(ajh1, bhf1, a, 0, 0, 0);
      a = __builtin_amdgcn_mfma_f32_16x16x32_bf16(ajl1, bhf1, a, 0, 0, 0);
      a = __builtin_amdgcn_mfma_f32_16x16x32_bf16(ajh1, blf1, a, 0, 0, 0);

      #pragma unroll
      for (int r = 0; r < 4; ++r) {
        float d2v = fmaf(-2.f, a[r], sqi + sq4[r]);
        d2v = fmaxf(d2v, 0.f);             // == reference clip(d2, 0)
        unsigned mx = (__float_as_uint(d2v) & 0xFFFFFF80u) | (lc + (unsigned)(jn*4 + r));
        #pragma unroll
        for (int t7 = 0; t7 < 7; ++t7) {
          unsigned old = k7[t7];
          k7[t7] = (mx < old) ? mx : old;
          mx     = (mx < old) ? old : mx;
        }
      }
    }
    if (c < 7) {
      *(uint4*)&Bh[nbuf][srow*72 + oct*8]      = gh0;
      *(uint4*)&Bh[nbuf][(srow+32)*72 + oct*8] = gh1;
      *(uint4*)&Bl[nbuf][srow*72 + oct*8]      = gl0;
      *(uint4*)&Bl[nbuf][(srow+32)*72 + oct*8] = gl1;
      if (tid < 64) sqjs[nbuf][tid] = gsq;
    }
    __syncthreads();
  }

  // unpack keys -> (truncated d2, global j); merge the row's 4 quads
  float* cd = (float*)&Bh[0][0];   // [64][28]
  int*   ci = (int*)&Bh[1][0];
  int row = w*16 + m;
  #pragma unroll
  for (int k = 0; k < 7; ++k) {
    unsigned key = k7[k];
    int local = key & 127;
    int cch = local >> 4, jn2 = (local >> 2) & 3, r2 = local & 3;
    cd[row*28 + quad*7 + k] = __uint_as_float(key & 0xFFFFFF80u);
    ci[row*28 + quad*7 + k] = jbase + cch*64 + jn2*16 + quad*4 + r2;
  }
  __syncthreads();
  if (tid < 64) {
    float md[7]; int mi[7];
    #pragma unroll
    for (int k = 0; k < 7; ++k) { md[k] = 3.0e38f; mi[k] = 0x7fffffff; }
    for (int e = 0; e < 28; ++e) {
      float d = cd[tid*28 + e]; int jj = ci[tid*28 + e];
      if (d < md[6] || (d == md[6] && jj < mi[6])) {
        int k = 6;
        #pragma unroll
        for (int t = 5; t >= 0; --t)
          if (d < md[t] || (d == md[t] && jj < mi[t])) { md[t+1] = md[t]; mi[t+1] = mi[t]; k = t; }
        md[k] = d; mi[k] = jj;
      }
    }
    int g = b*NN + i0 + tid;
    int base = (g*NCH + jsp)*7;
    #pragma unroll
    for (int k = 0; k < 7; ++k) { pd[base+k] = md[k]; pidx[base+k] = mi[k]; }
  }
}

// ---------------- K4: fused [hcat GEMM + f-vectors] and [top7 merge] --------
__global__ __launch_bounds__(256) void k_hm(const float* __restrict__ yn,
                                            const float* __restrict__ W0,
                                            const float* __restrict__ W1,
                                            const float* __restrict__ a0,
                                            const float* __restrict__ a1,
                                            float* __restrict__ hcat,
                                            float* __restrict__ fv,
                                            const float* __restrict__ pd,
                                            const int* __restrict__ pidx,
                                            int* __restrict__ nbr) {
  __shared__ __align__(16) float yt[16*64];
  int tid = threadIdx.x;
  if (blockIdx.x >= 512) {
    // ---- merge path ----
    int g = (blockIdx.x - 512)*256 + tid;    // 0..8191
    float d7[7]; int x7[7];
    #pragma unroll
    for (int k = 0; k < 7; ++k) { d7[k] = 3.0e38f; x7[k] = 0x7fffffff; }
    int base = g*NCH*7;
    for (int e = 0; e < NCH*7; ++e) {
      float d = pd[base+e]; int jj = pidx[base+e];
      if (d < d7[6]) {
        int k = 6;
        #pragma unroll
        for (int t = 5; t >= 0; --t) {
          if (d < d7[t]) { d7[t+1] = d7[t]; x7[t+1] = x7[t]; k = t; }
        }
        d7[k] = d; x7[k] = jj;
      }
    }
    #pragma unroll
    for (int k = 0; k < 7; ++k) nbr[g*7 + k] = x7[k];
    return;
  }
  // ---- hcat path ----
  int b = blockIdx.x >> 8, n0 = (blockIdx.x & 255)*16;
  int c = tid & 127, ng = tid >> 7, lane = tid & 63;
  float wreg[64];
  {
    const float* Wp = (c < 64) ? (W0 + c) : (W1 + (c - 64));
    #pragma unroll
    for (int k = 0; k < 64; ++k) wreg[k] = Wp[k*64];
  }
  ((float4*)yt)[tid] = ((const float4*)(yn + (b*NN + n0)*64))[tid];
  __syncthreads();
  int head = c >> 6;
  float av1 = head ? a1[lane] : a0[lane];
  float av2 = head ? a1[64 + lane] : a0[64 + lane];
  for (int nn = 0; nn < 8; ++nn) {
    int node = ng*8 + nn;
    const float* yr = yt + node*64;
    float acc = 0.f;
    #pragma unroll
    for (int k4 = 0; k4 < 16; ++k4) {
      float4 yv = *(const float4*)(yr + k4*4);
      acc = fmaf(yv.x, wreg[k4*4+0], acc);
      acc = fmaf(yv.y, wreg[k4*4+1], acc);
      acc = fmaf(yv.z, wreg[k4*4+2], acc);
      acc = fmaf(yv.w, wreg[k4*4+3], acc);
    }
    hcat[(b*NN + n0 + node)*128 + c] = acc;
    float s1 = acc*av1, s2 = acc*av2;
    #pragma unroll
    for (int off = 32; off > 0; off >>= 1) {
      s1 += __shfl_xor(s1, off); s2 += __shfl_xor(s2, off);
    }
    if (lane == 0) {
      int gg = (b << 12) + n0 + node;
      fv[head*16384 + gg] = s1;
      fv[head*16384 + 8192 + gg] = s2;
    }
  }
}

// ---------------- K6: GAT layer1 aggregation (2 heads) + relu ---------------
__global__ __launch_bounds__(256) void k_agg1(const float* __restrict__ hcat,
                                              const float* __restrict__ fv,
                                              const int* __restrict__ nbr,
                                              float* __restrict__ hagg) {
  int g = blockIdx.x*2 + (threadIdx.x >> 7);
  int c = threadIdx.x & 127;
  int b = g >> 12;
  int head = c >> 6;
  int jj[7];
  #pragma unroll
  for (int t = 0; t < 7; ++t) jj[t] = nbr[g*7 + t];
  float f1 = fv[head*16384 + g];
  const float* f2p = fv + head*16384 + 8192 + (b << 12);
  float e[7], mx = -3.0e38f;
  #pragma unroll
  for (int t = 0; t < 7; ++t) {
    float v = f1 + f2p[jj[t]];
    v = (v >= 0.f) ? v : 0.2f*v;
    e[t] = v; mx = fmaxf(mx, v);
  }
  float wgt[7], s = 0.f;
  #pragma unroll
  for (int t = 0; t < 7; ++t) { wgt[t] = expf(e[t] - mx); s += wgt[t]; }
  float acc = 0.f;
  #pragma unroll
  for (int t = 0; t < 7; ++t)
    acc += (wgt[t]/s) * hcat[((b << 12) + jj[t])*128 + c];
  hagg[g*128 + c] = fmaxf(acc, 0.f);
}

// ---------------- K7: ho = hagg @ W_out + fused f-vectors (reg-W halves) ----
__global__ __launch_bounds__(256) void k_ho(const float* __restrict__ hagg,
                                            const float* __restrict__ Wout,
                                            const float* __restrict__ aout,
                                            float* __restrict__ ho,
                                            float* __restrict__ fo) {
  __shared__ __align__(16) float ht[16*128];
  __shared__ float part[16][64];
  int b = blockIdx.x >> 8, n0 = (blockIdx.x & 255)*16;
  int tid = threadIdx.x;
  int c = tid & 63, g = (tid >> 6) & 1, ng = tid >> 7;
  float wreg[64];
  #pragma unroll
  for (int k = 0; k < 64; ++k) wreg[k] = Wout[(g*64 + k)*64 + c];
  {
    const float4* src = (const float4*)(hagg + (b*NN + n0)*128);
    ((float4*)ht)[tid] = src[tid];
    ((float4*)ht)[tid + 256] = src[tid + 256];
  }
  __syncthreads();
  float accs[8];
  for (int nn = 0; nn < 8; ++nn) {
    int node = ng*8 + nn;
    const float* hr = ht + node*128 + g*64;
    float acc = 0.f;
    #pragma unroll
    for (int k4 = 0; k4 < 16; ++k4) {
      float4 hv = *(const float4*)(hr + k4*4);
      acc = fmaf(hv.x, wreg[k4*4+0], acc);
      acc = fmaf(hv.y, wreg[k4*4+1], acc);
      acc = fmaf(hv.z, wreg[k4*4+2], acc);
      acc = fmaf(hv.w, wreg[k4*4+3], acc);
    }
    accs[nn] = acc;
  }
  if (g == 0) {
    #pragma unroll
    for (int nn = 0; nn < 8; ++nn) part[ng*8 + nn][c] = accs[nn];
  }
  __syncthreads();
  if (g == 1) {
    float av1 = aout[c], av2 = aout[64 + c];
    for (int nn = 0; nn < 8; ++nn) {
      int node = ng*8 + nn;
      float acc = accs[nn] + part[node][c];
      ho[(b*NN + n0 + node)*64 + c] = acc;
      float s1 = acc*av1, s2 = acc*av2;
      #pragma unroll
      for (int off = 32; off > 0; off >>= 1) {
        s1 += __shfl_xor(s1, off); s2 += __shfl_xor(s2, off);
      }
      if (c == 0) {
        int gg = (b << 12) + n0 + node;
        fo[gg] = s1;
        fo[8192 + gg] = s2;
      }
    }
  }
}

// ---------------- K9: layer2 agg + elu + log_softmax ------------------------
__global__ __launch_bounds__(256) void k_agg2(const float* __restrict__ ho,
                                              const float* __restrict__ fo,
                                              const int* __restrict__ nbr,
                                              float* __restrict__ zbuf) {
  int g = blockIdx.x*4 + (threadIdx.x >> 6);
  int c = threadIdx.x & 63;
  int b = g >> 12;
  int jj[7];
  #pragma unroll
  for (int t = 0; t < 7; ++t) jj[t] = nbr[g*7 + t];
  float f1 = fo[g];
  const float* f2p = fo + 8192 + (b << 12);
  float e[7], mx = -3.0e38f;
  #pragma unroll
  for (int t = 0; t < 7; ++t) {
    float v = f1 + f2p[jj[t]];
    v = (v >= 0.f) ? v : 0.2f*v;
    e[t] = v; mx = fmaxf(mx, v);
  }
  float wgt[7], s = 0.f;
  #pragma unroll
  for (int t = 0; t < 7; ++t) { wgt[t] = expf(e[t] - mx); s += wgt[t]; }
  float acc = 0.f;
  #pragma unroll
  for (int t = 0; t < 7; ++t)
    acc += (wgt[t]/s) * ho[((b << 12) + jj[t])*64 + c];
  float v = (acc > 0.f) ? acc : expm1f(acc);
  float mm = v;
  #pragma unroll
  for (int off = 32; off > 0; off >>= 1) mm = fmaxf(mm, __shfl_xor(mm, off));
  float ex = expf(v - mm), ss = ex;
  #pragma unroll
  for (int off = 32; off > 0; off >>= 1) ss += __shfl_xor(ss, off);
  zbuf[g*64 + c] = v - mm - logf(ss);
}

// ---------------- K10: ConvTranspose2d v4 — batched staging, 4 blocks/CU ----
// grid (128 oy, 2 xh, 2 b), 256 threads. Block computes [64 co][64 ox].
// Staging loads are register-batched (all loads issued, then LDS writes) to
// avoid per-iteration vmcnt(0) round-trips; launch_bounds caps VGPR for
// 4 blocks/CU residency.
__global__ __launch_bounds__(256, 4) void k_convt4(const float* __restrict__ z,
                                                   const float* __restrict__ wT,
                                                   const float* __restrict__ bias,
                                                   float* __restrict__ out) {
  __shared__ __align__(16) float lds[8704];    // 34816 B
  float* zt = lds;              // [2 rows][64 ci][36]
  float* ws = lds + 4608;       // [64 ci][64 co]
  float* so = lds;              // [64 co][65] epilogue alias

  int oy = blockIdx.x, xh = blockIdx.y, b = blockIdx.z;
  int r = oy >> 1, pi = oy & 1;
  int tid = threadIdx.x;
  int colo = tid & 15, pgrp = tid >> 4;
  int co4 = colo*4, m0 = pgrp*2;
  int ix0 = xh*32;

  // stage z slice (batched: 3 float4 loads, then scalar transpose writes)
  int nrows = pi ? 2 : 1;
  for (int row = 0; row < nrows; ++row) {
    int iy = r + row;
    const float* zsrc = z + (((b << 12) + iy*64) << 6);
    float4 v[3];
    #pragma unroll
    for (int j = 0; j < 3; ++j) {
      int chunk = tid + j*256;                 // 528 chunks = 33 ix x 16 ci4
      float4 vv = {0.f, 0.f, 0.f, 0.f};
      if (chunk < 528) {
        int ix = chunk >> 4, ci4 = (chunk & 15) << 2;
        int ixg = ix0 + ix;
        if (ixg < 64 && iy < 64) vv = *(const float4*)(zsrc + ixg*64 + ci4);
      }
      v[j] = vv;
    }
    #pragma unroll
    for (int j = 0; j < 3; ++j) {
      int chunk = tid + j*256;
      if (chunk < 528) {
        int ix = chunk >> 4, ci4 = (chunk & 15) << 2;
        zt[row*2304 + (ci4+0)*36 + ix] = v[j].x;
        zt[row*2304 + (ci4+1)*36 + ix] = v[j].y;
        zt[row*2304 + (ci4+2)*36 + ix] = v[j].z;
        zt[row*2304 + (ci4+3)*36 + ix] = v[j].w;
      }
    }
  }

  float acc[2][2][4];
  {
    float4 bv = *(const float4*)&bias[co4];
    #pragma unroll
    for (int chi = 0; chi < 2; ++chi)
      #pragma unroll
      for (int k = 0; k < 2; ++k) {
        acc[chi][k][0] = bv.x; acc[chi][k][1] = bv.y;
        acc[chi][k][2] = bv.z; acc[chi][k][3] = bv.w;
      }
  }

  int kys[2], rows[2], nky;
  if (pi == 0) { kys[0] = 1; rows[0] = 0; nky = 1; }
  else         { kys[0] = 2; rows[0] = 0; kys[1] = 0; rows[1] = 1; nky = 2; }

  for (int t = 0; t < nky; ++t) {
    const float* zrow = zt + rows[t]*2304;
    for (int kx = 0; kx < 3; ++kx) {
      const float* wsrc = wT + (kys[t]*3 + kx)*4096;
      __syncthreads();
      {
        // batched weight staging: 4 float4 loads, then 4 b128 LDS writes
        float4 wv4[4];
        #pragma unroll
        for (int j = 0; j < 4; ++j)
          wv4[j] = *(const float4*)(wsrc + (tid + j*256)*4);
        #pragma unroll
        for (int j = 0; j < 4; ++j)
          *(float4*)&ws[(tid + j*256)*4] = wv4[j];
      }
      __syncthreads();
      const int chi = (kx == 1) ? 0 : 1;
      const int xoff = (kx == 0) ? 1 : 0;
      float* ap = &acc[chi][0][0];
      for (int ci = 0; ci < 64; ++ci) {
        float4 wv = *(const float4*)&ws[ci*64 + co4];
        const float* zp = zrow + ci*36 + m0;
        float z0, z1;
        if (xoff == 0) { float2 za = *(const float2*)zp; z0 = za.x; z1 = za.y; }
        else           { float2 za = *(const float2*)zp; z0 = za.y; z1 = zp[2]; }
        ap[0] = fmaf(z0, wv.x, ap[0]);
        ap[1] = fmaf(z0, wv.y, ap[1]);
        ap[2] = fmaf(z0, wv.z, ap[2]);
        ap[3] = fmaf(z0, wv.w, ap[3]);
        ap[4] = fmaf(z1, wv.x, ap[4]);
        ap[5] = fmaf(z1, wv.y, ap[5]);
        ap[6] = fmaf(z1, wv.z, ap[6]);
        ap[7] = fmaf(z1, wv.w, ap[7]);
      }
    }
  }

  __syncthreads();
  #pragma unroll
  for (int chi = 0; chi < 2; ++chi)
    #pragma unroll
    for (int k = 0; k < 2; ++k)
      #pragma unroll
      for (int cc = 0; cc < 4; ++cc)
        so[(co4 + cc)*65 + 2*(m0 + k) + chi] = acc[chi][k][cc];
  __syncthreads();
  for (int idx = tid; idx < 4096; idx += 256) {
    int co = idx >> 6, ox = idx & 63;
    out[(((b << 6) + co)*128 + oy)*128 + xh*64 + ox] = so[co*65 + ox];
  }
}

// ---------------- launch ----------------------------------------------------
extern "C" void kernel_launch(void* const* d_in, const int* in_sizes, int n_in,
                              void* d_out, int out_size, void* d_ws, size_t ws_size,
                              hipStream_t stream) {
  const float* x      = (const float*)d_in[0];
  const float* w_head = (const float*)d_in[1];
  const float* b_head = (const float*)d_in[2];
  const float* W0     = (const float*)d_in[3];
  const float* a0     = (const float*)d_in[4];
  const float* W1     = (const float*)d_in[5];
  const float* a1     = (const float*)d_in[6];
  const float* W_out  = (const float*)d_in[7];
  const float* a_out  = (const float*)d_in[8];
  const float* w_last = (const float*)d_in[9];
  const float* b_last = (const float*)d_in[10];
  float* out = (float*)d_out;

  float* wsf = (float*)d_ws;
  int*   wsi = (int*)d_ws;
  float* yn   = wsf + OF_YN;
  float* sq   = wsf + OF_SQ;
  float* hcat = wsf + OF_HCAT;
  float* fv   = wsf + OF_FV;
  float* hagg = wsf + OF_HAGG;
  float* ho   = wsf + OF_HO;
  float* fo   = wsf + OF_FO;
  float* zbuf = wsf + OF_Z;
  float* pd   = wsf + OF_PD;
  int*   pidx = wsi + OF_PI;
  int*   nbr  = wsi + OF_NBR;
  float* wT   = wsf + OF_WT;
  float* whT  = wsf + OF_WHT;
  unsigned short* ynh = (unsigned short*)(wsf + OF_YNH);
  unsigned short* ynl = (unsigned short*)(wsf + OF_YNL);

  hipLaunchKernelGGL(k_prep,  dim3(214), dim3(256), 0, stream, w_last, w_head, wT, whT);
  hipLaunchKernelGGL(k_head,  dim3(1024), dim3(256), 0, stream, x, whT, b_head, yn, sq, ynh, ynl);
  hipLaunchKernelGGL(k_knn6,  dim3(64, NCH, 2), dim3(256), 0, stream, ynh, ynl, sq, pd, pidx);
  hipLaunchKernelGGL(k_hm,    dim3(544), dim3(256), 0, stream, yn, W0, W1, a0, a1, hcat, fv, pd, pidx, nbr);
  hipLaunchKernelGGL(k_agg1,  dim3(4096), dim3(256), 0, stream, hcat, fv, nbr, hagg);
  hipLaunchKernelGGL(k_ho,    dim3(512), dim3(256), 0, stream, hagg, W_out, a_out, ho, fo);
  hipLaunchKernelGGL(k_agg2,  dim3(2048), dim3(256), 0, stream, ho, fo, nbr, zbuf);
  hipLaunchKernelGGL(k_convt4, dim3(128, 2, 2), dim3(256), 0, stream, zbuf, wT, b_last, out);
}